// Round 4
// baseline (299.642 us; speedup 1.0000x reference)
//
#include <hip/hip_runtime.h>
#include <hip/hip_bf16.h>
#include <stdint.h>
#include <math.h>

// Problem dims (fixed)
#define NB  4
#define NS  2048
#define ND  768
#define NHD 12
#define NDK 64
#define NBH (NB*NHD)   // 48

// Q pre-scale: 1/sqrt(DK) * log2(e) so passes use raw exp2
#define QSCALE 0.180336879f

typedef short short8 __attribute__((ext_vector_type(8)));
typedef float f32x4  __attribute__((ext_vector_type(4)));
typedef float f32x16 __attribute__((ext_vector_type(16)));
typedef unsigned int uint2v __attribute__((ext_vector_type(2)));

#define MFMA16(a,b,c) __builtin_amdgcn_mfma_f32_16x16x32_bf16(a,b,c,0,0,0)
#define MFMA32(a,b,c) __builtin_amdgcn_mfma_f32_32x32x16_bf16(a,b,c,0,0,0)

__device__ __forceinline__ short f2b(float f){
  union { float f; uint32_t u; } v; v.f = f;
  uint32_t u = v.u + 0x7fffu + ((v.u >> 16) & 1u);  // RNE
  return (short)(u >> 16);
}
__device__ __forceinline__ float b2f(short s){
  union { float f; uint32_t u; } v; v.u = ((uint32_t)(unsigned short)s) << 16; return v.f;
}
__device__ __forceinline__ uint32_t cvtpk(float lo, float hi){
  uint32_t r;
  asm("v_cvt_pk_bf16_f32 %0, %1, %2" : "=v"(r) : "v"(lo), "v"(hi));
  return r;
}
__device__ __forceinline__ short8 mk8(uint32_t a, uint32_t b, uint32_t c, uint32_t d){
  union { uint32_t u[4]; short8 v; } x;
  x.u[0]=a; x.u[1]=b; x.u[2]=c; x.u[3]=d; return x.v;
}

__device__ __forceinline__ void gload16(const void* g, void* lds){
  __builtin_amdgcn_global_load_lds(
      (const __attribute__((address_space(1))) uint32_t*)g,
      (__attribute__((address_space(3))) uint32_t*)lds, 16, 0, 0);
}

// ---------------- elementwise fp32 -> bf16 cast ----------------
__global__ __launch_bounds__(256) void cast_f2bf(const float* __restrict__ in,
                                                 short* __restrict__ out, int n8){
  int i = blockIdx.x * 256 + threadIdx.x;
  if (i < n8){
    const f32x4* p = (const f32x4*)(in + (size_t)i*8);
    f32x4 v0 = p[0], v1 = p[1];
    short8 r;
    r[0]=f2b(v0[0]); r[1]=f2b(v0[1]); r[2]=f2b(v0[2]); r[3]=f2b(v0[3]);
    r[4]=f2b(v1[0]); r[5]=f2b(v1[1]); r[6]=f2b(v1[2]); r[7]=f2b(v1[3]);
    *(short8*)(out + (size_t)i*8) = r;
  }
}

// ---------------- 128x128x(K=768) bf16 GEMM core (m97 structure) ----------------
__device__ __forceinline__ void gemm128_core(const short* __restrict__ A,
                                             const short* __restrict__ Bw,
                                             int rowA0, int rowB0,
                                             short* As, short* Bs, f32x4 acc[4][4]){
  const int t = threadIdx.x;
  const int l  = t & 63;
  const int wm = ((t >> 7) & 1) * 64;
  const int wn = ((t >> 6) & 1) * 64;
  const int lr = l & 15, lg = l >> 4;
  #pragma unroll
  for (int mt=0; mt<4; ++mt)
    #pragma unroll
    for (int nt=0; nt<4; ++nt) acc[mt][nt] = (f32x4){0.f,0.f,0.f,0.f};

  for (int kt = 0; kt < 12; ++kt){
    #pragma unroll
    for (int c = 0; c < 4; ++c){
      int u  = c*256 + t;
      int m  = u >> 3;
      int kb = ((u & 7) << 4) ^ ((m & 7) << 4);   // inverse-swizzled source
      gload16((const char*)(A  + (size_t)(rowA0 + m)*768 + kt*64) + kb,
              (char*)As + ((c*256 + (t & 0xC0)) << 4));
      gload16((const char*)(Bw + (size_t)(rowB0 + m)*768 + kt*64) + kb,
              (char*)Bs + ((c*256 + (t & 0xC0)) << 4));
    }
    __syncthreads();
    short8 af[4][2], bf[4][2];
    #pragma unroll
    for (int mt=0; mt<4; ++mt)
      #pragma unroll
      for (int ks=0; ks<2; ++ks){
        int m  = wm + mt*16 + lr;
        int kb = (ks*32 + lg*8) * 2;
        af[mt][ks] = *(const short8*)((const char*)As + ((m*128 + kb) ^ ((m & 7) << 4)));
        int n  = wn + mt*16 + lr;
        bf[mt][ks] = *(const short8*)((const char*)Bs + ((n*128 + kb) ^ ((n & 7) << 4)));
      }
    #pragma unroll
    for (int mt=0; mt<4; ++mt)
      #pragma unroll
      for (int nt=0; nt<4; ++nt){
        acc[mt][nt] = MFMA16(af[mt][0], bf[nt][0], acc[mt][nt]);
        acc[mt][nt] = MFMA16(af[mt][1], bf[nt][1], acc[mt][nt]);
      }
    __syncthreads();
  }
}

// QKV fused: grid (64, 18). Q/K written in fragment-packed layout:
//   Xf[((bh*64 + (s>>5))*4 + (dk>>4))*512 + ((dk>>3)&1)*256 + (s&31)*8 + (dk&7)]
// Q pre-scaled by QSCALE. V written row-major (b,s,h,dk) for pack_v.
__global__ __launch_bounds__(256) void gemm_qkv(const short* __restrict__ Xb,
    const short* __restrict__ Wqb, const short* __restrict__ Wkb, const short* __restrict__ Wvb,
    short* __restrict__ Qf, short* __restrict__ Kf, short* __restrict__ V){
  __shared__ __align__(16) short As[128*64];
  __shared__ __align__(16) short Bs[128*64];
  const int wsel = blockIdx.y / 6;
  const int nb   = (blockIdx.y % 6) * 128;
  const short* W = (wsel==0) ? Wqb : ((wsel==1) ? Wkb : Wvb);
  f32x4 acc[4][4];
  gemm128_core(Xb, W, blockIdx.x*128, nb, As, Bs, acc);
  const int t = threadIdx.x, l = t & 63;
  const int wm = ((t>>7)&1)*64, wn = ((t>>6)&1)*64;
  const int lr = l & 15, lg = l >> 4;
  if (wsel == 2){
    #pragma unroll
    for (int mt=0; mt<4; ++mt)
      #pragma unroll
      for (int nt=0; nt<4; ++nt)
        #pragma unroll
        for (int r=0; r<4; ++r){
          int m = blockIdx.x*128 + wm + mt*16 + lg*4 + r;
          int n = nb + wn + nt*16 + lr;
          V[(size_t)m*768 + n] = f2b(acc[mt][nt][r]);
        }
  } else {
    short* O = (wsel==0) ? Qf : Kf;
    const float scl = (wsel==0) ? QSCALE : 1.0f;
    const int bh = (blockIdx.x >> 4)*NHD + ((nb + wn) >> 6);
    const int s0 = (blockIdx.x & 15)*128 + wm;
    short* Ob = O + (size_t)bh*131072;   // 64 kt * 2048
    #pragma unroll
    for (int mt=0; mt<4; ++mt)
      #pragma unroll
      for (int nt=0; nt<4; ++nt)
        #pragma unroll
        for (int r=0; r<4; ++r){
          int s  = s0 + mt*16 + lg*4 + r;
          int dk = nt*16 + lr;
          Ob[(size_t)((s>>5)*4 + (dk>>4))*512 + ((dk>>3)&1)*256 + (s&31)*8 + (dk&7)]
            = f2b(acc[mt][nt][r] * scl);
        }
  }
}

// Final projection: grid (64, 6). fp32 output.
__global__ __launch_bounds__(256) void gemm_out(const short* __restrict__ Hb,
    const short* __restrict__ W0b, float* __restrict__ out){
  __shared__ __align__(16) short As[128*64];
  __shared__ __align__(16) short Bs[128*64];
  const int nb = blockIdx.y * 128;
  f32x4 acc[4][4];
  gemm128_core(Hb, W0b, blockIdx.x*128, nb, As, Bs, acc);
  const int t = threadIdx.x, l = t & 63;
  const int wm = ((t>>7)&1)*64, wn = ((t>>6)&1)*64;
  const int lr = l & 15, lg = l >> 4;
  #pragma unroll
  for (int mt=0; mt<4; ++mt)
    #pragma unroll
    for (int nt=0; nt<4; ++nt)
      #pragma unroll
      for (int r=0; r<4; ++r){
        int m = blockIdx.x*128 + wm + mt*16 + lg*4 + r;
        int n = nb + wn + nt*16 + lr;
        out[(size_t)m*768 + n] = acc[mt][nt][r];
      }
}

// Pass A: colsum over the QUERY axis. grid (64,48): block = one 32-kv tile of
// one bh; wave w covers q-tiles [w*16, w*16+16). XCD-swizzled so each bh's
// blocks share an XCD (L2 reuse of Q). Cross-wave combine via tiny LDS.
__global__ __launch_bounds__(256, 8) void pass_a(const short* __restrict__ Qf,
                                                 const short* __restrict__ Kf,
                                                 float* __restrict__ invs){
  __shared__ float redA[4][32];
  const int t = threadIdx.x, w = t >> 6, l = t & 63;
  const int lq = l & 31, hf = l >> 5;
  const int linear = blockIdx.y * 64 + blockIdx.x;   // 3072 blocks
  const int c8 = linear & 7, j = linear >> 3;
  const int bh = c8 * 6 + (j >> 6);
  const int kt0 = j & 63;

  const short8* Kg = (const short8*)(Kf + ((size_t)bh*64 + kt0)*2048);
  short8 kf4[4];
  #pragma unroll
  for (int c=0; c<4; ++c) kf4[c] = Kg[c*64 + l];

  float psum[16];
  #pragma unroll
  for (int r=0; r<16; ++r) psum[r] = 0.f;

  const short8* Qb = (const short8*)(Qf + (size_t)bh*131072);
  for (int qt = w*16; qt < w*16 + 16; ++qt){
    const short8* Qg = Qb + qt*256;
    short8 q0 = Qg[l], q1 = Qg[64+l], q2 = Qg[128+l], q3 = Qg[192+l];
    f32x16 c = {};
    c = MFMA32(kf4[0], q0, c);
    c = MFMA32(kf4[1], q1, c);
    c = MFMA32(kf4[2], q2, c);
    c = MFMA32(kf4[3], q3, c);
    #pragma unroll
    for (int r=0; r<16; ++r) psum[r] += exp2f(c[r]);
  }
  #pragma unroll
  for (int r=0; r<16; ++r){
    float v = psum[r];
    v += __shfl_xor(v, 1); v += __shfl_xor(v, 2);
    v += __shfl_xor(v, 4); v += __shfl_xor(v, 8); v += __shfl_xor(v, 16);
    if (lq == 0) redA[w][(r&3) + 8*(r>>2) + 4*hf] = v;
  }
  __syncthreads();
  if (t < 32){
    float s = redA[0][t] + redA[1][t] + redA[2][t] + redA[3][t];
    invs[(size_t)bh*NS + kt0*32 + t] = 1.0f / s;
  }
}

// V (b,s,h,dk) -> Vf fragment-packed with inverse colsum folded in.
__global__ __launch_bounds__(256) void pack_v(const short* __restrict__ V,
                                              const float* __restrict__ invs,
                                              short* __restrict__ Vf){
  __shared__ short tile[64][66];
  const int sb = blockIdx.x * 64;
  const int bh = blockIdx.y;
  const int b = bh / NHD, h = bh % NHD;
  const int t = threadIdx.x;
  {
    int r = t >> 2, dkb = (t & 3) * 16;
    float iv = invs[(size_t)bh*NS + sb + r];
    const short* src = V + ((size_t)(b*NS + sb + r)*NHD + h)*NDK + dkb;
    short8 v0 = *(const short8*)src;
    short8 v1 = *(const short8*)(src + 8);
    #pragma unroll
    for (int j=0;j<8;++j) tile[r][dkb+j]   = f2b(b2f(v0[j]) * iv);
    #pragma unroll
    for (int j=0;j<8;++j) tile[r][dkb+8+j] = f2b(b2f(v1[j]) * iv);
  }
  __syncthreads();
  {
    const int c = t >> 6, l = t & 63;
    const int lq = l & 31, hf = l >> 5;
    const int dk = (c>>1)*32 + lq;
    #pragma unroll
    for (int kt_l = 0; kt_l < 2; ++kt_l){
      int kv0 = kt_l*32 + (c&1)*16 + hf*8;
      short8 o;
      #pragma unroll
      for (int j=0;j<8;++j) o[j] = tile[kv0+j][dk];
      *(short8*)(Vf + (((size_t)bh*64 + (sb>>5) + kt_l)*256 + c*64 + l)*8) = o;
    }
  }
}

// Pass C: grid (64,48): block = one 32-q tile; wave w covers kv-tiles
// [w*16, w*16+16); partial O combined via 16KB LDS tree. XCD-swizzled.
__global__ __launch_bounds__(256, 8) void pass_c(const short* __restrict__ Qf,
                                                 const short* __restrict__ Kf,
                                                 const short* __restrict__ Vf,
                                                 short* __restrict__ Hd){
  __shared__ float red[2][32][64];   // 16 KB
  const int t = threadIdx.x, w = t >> 6, l = t & 63;
  const int lq = l & 31, hf = l >> 5;
  const int linear = blockIdx.y * 64 + blockIdx.x;   // 3072 blocks
  const int c8 = linear & 7, j = linear >> 3;
  const int bh = c8 * 6 + (j >> 6);
  const int qt = j & 63;

  const short8* Qg = (const short8*)(Qf + ((size_t)bh*64 + qt)*2048);
  short8 qf4[4];
  #pragma unroll
  for (int c=0; c<4; ++c) qf4[c] = Qg[c*64 + l];

  const short8* Kb = (const short8*)(Kf + (size_t)bh*131072);
  const short8* Vb = (const short8*)(Vf + (size_t)bh*131072);

  f32x16 acc0 = {}, acc1 = {};   // heads[q][dk] halves

  for (int kt = w*16; kt < w*16 + 16; ++kt){
    const short8* Kg = Kb + kt*256;
    const short8* Vg = Vb + kt*256;
    short8 k0 = Kg[l], k1 = Kg[64+l], k2 = Kg[128+l], k3 = Kg[192+l];
    short8 v0 = Vg[l], v1 = Vg[64+l], v2 = Vg[128+l], v3 = Vg[192+l];

    f32x16 c = {};
    c = MFMA32(k0, qf4[0], c);
    c = MFMA32(k1, qf4[1], c);
    c = MFMA32(k2, qf4[2], c);
    c = MFMA32(k3, qf4[3], c);

    float p[16];
    #pragma unroll
    for (int r=0; r<16; ++r) p[r] = exp2f(c[r]);

    short8 pa[2];
    #pragma unroll
    for (int b2=0; b2<2; ++b2){
      uint32_t x0 = cvtpk(p[8*b2+0], p[8*b2+1]);
      uint32_t x1 = cvtpk(p[8*b2+2], p[8*b2+3]);
      uint32_t y0 = cvtpk(p[8*b2+4], p[8*b2+5]);
      uint32_t y1 = cvtpk(p[8*b2+6], p[8*b2+7]);
      uint2v r02 = __builtin_amdgcn_permlane32_swap(x0, y0, false, false);
      uint2v r13 = __builtin_amdgcn_permlane32_swap(x1, y1, false, false);
      pa[b2] = mk8(r02.x, r13.x, r02.y, r13.y);
    }
    acc0 = MFMA32(pa[0], v0, acc0);
    acc0 = MFMA32(pa[1], v1, acc0);
    acc1 = MFMA32(pa[0], v2, acc1);
    acc1 = MFMA32(pa[1], v3, acc1);
  }

  // cross-wave reduction: waves 2,3 -> LDS; waves 0,1 add; wave 1 -> LDS;
  // wave 0 adds and stores.
  if (w >= 2){
    #pragma unroll
    for (int r=0; r<16; ++r){
      red[w-2][r][l]    = acc0[r];
      red[w-2][16+r][l] = acc1[r];
    }
  }
  __syncthreads();
  if (w < 2){
    #pragma unroll
    for (int r=0; r<16; ++r){
      acc0[r] += red[w][r][l];
      acc1[r] += red[w][16+r][l];
    }
  }
  __syncthreads();
  if (w == 1){
    #pragma unroll
    for (int r=0; r<16; ++r){
      red[0][r][l]    = acc0[r];
      red[0][16+r][l] = acc1[r];
    }
  }
  __syncthreads();
  if (w == 0){
    #pragma unroll
    for (int r=0; r<16; ++r){
      acc0[r] += red[0][r][l];
      acc1[r] += red[0][16+r][l];
      int q = qt*32 + (r&3) + 8*(r>>2) + 4*hf;
      short* dst = Hd + ((size_t)bh*NS + q)*NDK;
      dst[lq]      = f2b(acc0[r]);
      dst[32 + lq] = f2b(acc1[r]);
    }
  }
}

extern "C" void kernel_launch(void* const* d_in, const int* in_sizes, int n_in,
                              void* d_out, int out_size, void* d_ws, size_t ws_size,
                              hipStream_t stream){
  (void)in_sizes; (void)n_in; (void)out_size; (void)ws_size;
  const float* x  = (const float*)d_in[0];
  const float* Wq = (const float*)d_in[1];
  const float* Wk = (const float*)d_in[2];
  const float* Wv = (const float*)d_in[3];
  const float* W0 = (const float*)d_in[4];

  char* ws = (char*)d_ws;
  const size_t SZ_X = (size_t)NB*NS*ND*2;   // 12,582,912 B
  const size_t SZ_W = (size_t)ND*ND*2;      //  1,179,648 B
  short* Xb   = (short*)(ws);               // reused as Hd after QKV GEMM
  short* Wqb  = (short*)(ws + SZ_X);
  short* Wkb  = (short*)(ws + SZ_X + 1*SZ_W);
  short* Wvb  = (short*)(ws + SZ_X + 2*SZ_W);
  short* W0b  = (short*)(ws + SZ_X + 3*SZ_W);
  short* Qf   = (short*)(ws + 1*SZ_X + 4*SZ_W);
  short* Kf   = (short*)(ws + 2*SZ_X + 4*SZ_W);
  short* V    = (short*)(ws + 3*SZ_X + 4*SZ_W);
  short* Vf   = (short*)(ws + 4*SZ_X + 4*SZ_W);
  float* invs = (float*)(ws + 5*SZ_X + 4*SZ_W);
  short* Hd   = Xb;
  float* out  = (float*)d_out;

  cast_f2bf<<<dim3(3072), dim3(256), 0, stream>>>(x,  Xb,  NB*NS*ND/8);
  cast_f2bf<<<dim3(288),  dim3(256), 0, stream>>>(Wq, Wqb, ND*ND/8);
  cast_f2bf<<<dim3(288),  dim3(256), 0, stream>>>(Wk, Wkb, ND*ND/8);
  cast_f2bf<<<dim3(288),  dim3(256), 0, stream>>>(Wv, Wvb, ND*ND/8);
  cast_f2bf<<<dim3(288),  dim3(256), 0, stream>>>(W0, W0b, ND*ND/8);

  gemm_qkv<<<dim3(64,18), dim3(256), 0, stream>>>(Xb, Wqb, Wkb, Wvb, Qf, Kf, V);
  pass_a<<<dim3(64,48), dim3(256), 0, stream>>>(Qf, Kf, invs);
  pack_v<<<dim3(32,48), dim3(256), 0, stream>>>(V, invs, Vf);
  pass_c<<<dim3(64,48), dim3(256), 0, stream>>>(Qf, Kf, Vf, Hd);
  gemm_out<<<dim3(64,6), dim3(256), 0, stream>>>(Hd, W0b, out);
}

// Round 5
// 231.618 us; speedup vs baseline: 1.2937x; 1.2937x over previous
//
#include <hip/hip_runtime.h>
#include <hip/hip_bf16.h>
#include <stdint.h>
#include <math.h>

// Problem dims (fixed)
#define NB  4
#define NS  2048
#define ND  768
#define NHD 12
#define NDK 64
#define NBH (NB*NHD)   // 48

// Q pre-scale: 1/sqrt(DK) * log2(e) so passes use raw exp2
#define QSCALE 0.180336879f

typedef short short8 __attribute__((ext_vector_type(8)));
typedef float f32x4  __attribute__((ext_vector_type(4)));
typedef float f32x16 __attribute__((ext_vector_type(16)));
typedef unsigned int uint2v __attribute__((ext_vector_type(2)));

#define MFMA16(a,b,c) __builtin_amdgcn_mfma_f32_16x16x32_bf16(a,b,c,0,0,0)
#define MFMA32(a,b,c) __builtin_amdgcn_mfma_f32_32x32x16_bf16(a,b,c,0,0,0)

__device__ __forceinline__ short f2b(float f){
  union { float f; uint32_t u; } v; v.f = f;
  uint32_t u = v.u + 0x7fffu + ((v.u >> 16) & 1u);  // RNE
  return (short)(u >> 16);
}
__device__ __forceinline__ float b2f(short s){
  union { float f; uint32_t u; } v; v.u = ((uint32_t)(unsigned short)s) << 16; return v.f;
}
__device__ __forceinline__ uint32_t cvtpk(float lo, float hi){
  uint32_t r;
  asm("v_cvt_pk_bf16_f32 %0, %1, %2" : "=v"(r) : "v"(lo), "v"(hi));
  return r;
}
__device__ __forceinline__ short8 mk8(uint32_t a, uint32_t b, uint32_t c, uint32_t d){
  union { uint32_t u[4]; short8 v; } x;
  x.u[0]=a; x.u[1]=b; x.u[2]=c; x.u[3]=d; return x.v;
}

__device__ __forceinline__ void gload16(const void* g, void* lds){
  __builtin_amdgcn_global_load_lds(
      (const __attribute__((address_space(1))) uint32_t*)g,
      (__attribute__((address_space(3))) uint32_t*)lds, 16, 0, 0);
}

// ---------------- elementwise fp32 -> bf16 cast ----------------
__global__ __launch_bounds__(256) void cast_f2bf(const float* __restrict__ in,
                                                 short* __restrict__ out, int n8){
  int i = blockIdx.x * 256 + threadIdx.x;
  if (i < n8){
    const f32x4* p = (const f32x4*)(in + (size_t)i*8);
    f32x4 v0 = p[0], v1 = p[1];
    short8 r;
    r[0]=f2b(v0[0]); r[1]=f2b(v0[1]); r[2]=f2b(v0[2]); r[3]=f2b(v0[3]);
    r[4]=f2b(v1[0]); r[5]=f2b(v1[1]); r[6]=f2b(v1[2]); r[7]=f2b(v1[3]);
    *(short8*)(out + (size_t)i*8) = r;
  }
}

// ---------------- 128x128x(K=768) bf16 GEMM core (m97 structure) ----------------
__device__ __forceinline__ void gemm128_core(const short* __restrict__ A,
                                             const short* __restrict__ Bw,
                                             int rowA0, int rowB0,
                                             short* As, short* Bs, f32x4 acc[4][4]){
  const int t = threadIdx.x;
  const int l  = t & 63;
  const int wm = ((t >> 7) & 1) * 64;
  const int wn = ((t >> 6) & 1) * 64;
  const int lr = l & 15, lg = l >> 4;
  #pragma unroll
  for (int mt=0; mt<4; ++mt)
    #pragma unroll
    for (int nt=0; nt<4; ++nt) acc[mt][nt] = (f32x4){0.f,0.f,0.f,0.f};

  for (int kt = 0; kt < 12; ++kt){
    #pragma unroll
    for (int c = 0; c < 4; ++c){
      int u  = c*256 + t;
      int m  = u >> 3;
      int kb = ((u & 7) << 4) ^ ((m & 7) << 4);   // inverse-swizzled source
      gload16((const char*)(A  + (size_t)(rowA0 + m)*768 + kt*64) + kb,
              (char*)As + ((c*256 + (t & 0xC0)) << 4));
      gload16((const char*)(Bw + (size_t)(rowB0 + m)*768 + kt*64) + kb,
              (char*)Bs + ((c*256 + (t & 0xC0)) << 4));
    }
    __syncthreads();
    short8 af[4][2], bf[4][2];
    #pragma unroll
    for (int mt=0; mt<4; ++mt)
      #pragma unroll
      for (int ks=0; ks<2; ++ks){
        int m  = wm + mt*16 + lr;
        int kb = (ks*32 + lg*8) * 2;
        af[mt][ks] = *(const short8*)((const char*)As + ((m*128 + kb) ^ ((m & 7) << 4)));
        int n  = wn + mt*16 + lr;
        bf[mt][ks] = *(const short8*)((const char*)Bs + ((n*128 + kb) ^ ((n & 7) << 4)));
      }
    #pragma unroll
    for (int mt=0; mt<4; ++mt)
      #pragma unroll
      for (int nt=0; nt<4; ++nt){
        acc[mt][nt] = MFMA16(af[mt][0], bf[nt][0], acc[mt][nt]);
        acc[mt][nt] = MFMA16(af[mt][1], bf[nt][1], acc[mt][nt]);
      }
    __syncthreads();
  }
}

// QKV fused: grid (64, 18). Q/K written in fragment-packed layout:
//   Xf[((bh*64 + (s>>5))*4 + (dk>>4))*512 + ((dk>>3)&1)*256 + (s&31)*8 + (dk&7)]
// Q pre-scaled by QSCALE. V written row-major (b,s,h,dk) for pack_v.
__global__ __launch_bounds__(256) void gemm_qkv(const short* __restrict__ Xb,
    const short* __restrict__ Wqb, const short* __restrict__ Wkb, const short* __restrict__ Wvb,
    short* __restrict__ Qf, short* __restrict__ Kf, short* __restrict__ V){
  __shared__ __align__(16) short As[128*64];
  __shared__ __align__(16) short Bs[128*64];
  const int wsel = blockIdx.y / 6;
  const int nb   = (blockIdx.y % 6) * 128;
  const short* W = (wsel==0) ? Wqb : ((wsel==1) ? Wkb : Wvb);
  f32x4 acc[4][4];
  gemm128_core(Xb, W, blockIdx.x*128, nb, As, Bs, acc);
  const int t = threadIdx.x, l = t & 63;
  const int wm = ((t>>7)&1)*64, wn = ((t>>6)&1)*64;
  const int lr = l & 15, lg = l >> 4;
  if (wsel == 2){
    #pragma unroll
    for (int mt=0; mt<4; ++mt)
      #pragma unroll
      for (int nt=0; nt<4; ++nt)
        #pragma unroll
        for (int r=0; r<4; ++r){
          int m = blockIdx.x*128 + wm + mt*16 + lg*4 + r;
          int n = nb + wn + nt*16 + lr;
          V[(size_t)m*768 + n] = f2b(acc[mt][nt][r]);
        }
  } else {
    short* O = (wsel==0) ? Qf : Kf;
    const float scl = (wsel==0) ? QSCALE : 1.0f;
    const int bh = (blockIdx.x >> 4)*NHD + ((nb + wn) >> 6);
    const int s0 = (blockIdx.x & 15)*128 + wm;
    short* Ob = O + (size_t)bh*131072;   // 64 kt * 2048
    #pragma unroll
    for (int mt=0; mt<4; ++mt)
      #pragma unroll
      for (int nt=0; nt<4; ++nt)
        #pragma unroll
        for (int r=0; r<4; ++r){
          int s  = s0 + mt*16 + lg*4 + r;
          int dk = nt*16 + lr;
          Ob[(size_t)((s>>5)*4 + (dk>>4))*512 + ((dk>>3)&1)*256 + (s&31)*8 + (dk&7)]
            = f2b(acc[mt][nt][r] * scl);
        }
  }
}

// Final projection: grid (64, 6). fp32 output.
__global__ __launch_bounds__(256) void gemm_out(const short* __restrict__ Hb,
    const short* __restrict__ W0b, float* __restrict__ out){
  __shared__ __align__(16) short As[128*64];
  __shared__ __align__(16) short Bs[128*64];
  const int nb = blockIdx.y * 128;
  f32x4 acc[4][4];
  gemm128_core(Hb, W0b, blockIdx.x*128, nb, As, Bs, acc);
  const int t = threadIdx.x, l = t & 63;
  const int wm = ((t>>7)&1)*64, wn = ((t>>6)&1)*64;
  const int lr = l & 15, lg = l >> 4;
  #pragma unroll
  for (int mt=0; mt<4; ++mt)
    #pragma unroll
    for (int nt=0; nt<4; ++nt)
      #pragma unroll
      for (int r=0; r<4; ++r){
        int m = blockIdx.x*128 + wm + mt*16 + lg*4 + r;
        int n = nb + wn + nt*16 + lr;
        out[(size_t)m*768 + n] = acc[mt][nt][r];
      }
}

// Pass A: colsum over the QUERY axis. grid (64,48): block = one 32-kv tile of
// one bh; wave w covers q-tiles [w*16, w*16+16). XCD-swizzled (bijective,
// 3072%8==0). min-waves=4 (VGPR cap 128): round-4's =8 capped at 64 and
// SPILLED (VGPR_Count=32, WRITE_SIZE 67MB scratch traffic) — do not repeat.
__global__ __launch_bounds__(256, 4) void pass_a(const short* __restrict__ Qf,
                                                 const short* __restrict__ Kf,
                                                 float* __restrict__ invs){
  __shared__ float redA[4][32];
  const int t = threadIdx.x, w = t >> 6, l = t & 63;
  const int lq = l & 31, hf = l >> 5;
  const int linear = blockIdx.y * 64 + blockIdx.x;   // 3072 blocks
  const int c8 = linear & 7, j = linear >> 3;
  const int bh = c8 * 6 + (j >> 6);
  const int kt0 = j & 63;

  const short8* Kg = (const short8*)(Kf + ((size_t)bh*64 + kt0)*2048);
  short8 kf4[4];
  #pragma unroll
  for (int c=0; c<4; ++c) kf4[c] = Kg[c*64 + l];

  float psum[16];
  #pragma unroll
  for (int r=0; r<16; ++r) psum[r] = 0.f;

  const short8* Qb = (const short8*)(Qf + (size_t)bh*131072);
  for (int qt = w*16; qt < w*16 + 16; ++qt){
    const short8* Qg = Qb + qt*256;
    short8 q0 = Qg[l], q1 = Qg[64+l], q2 = Qg[128+l], q3 = Qg[192+l];
    f32x16 c = {};
    c = MFMA32(kf4[0], q0, c);
    c = MFMA32(kf4[1], q1, c);
    c = MFMA32(kf4[2], q2, c);
    c = MFMA32(kf4[3], q3, c);
    #pragma unroll
    for (int r=0; r<16; ++r) psum[r] += exp2f(c[r]);
  }
  #pragma unroll
  for (int r=0; r<16; ++r){
    float v = psum[r];
    v += __shfl_xor(v, 1); v += __shfl_xor(v, 2);
    v += __shfl_xor(v, 4); v += __shfl_xor(v, 8); v += __shfl_xor(v, 16);
    if (lq == 0) redA[w][(r&3) + 8*(r>>2) + 4*hf] = v;
  }
  __syncthreads();
  if (t < 32){
    float s = redA[0][t] + redA[1][t] + redA[2][t] + redA[3][t];
    invs[(size_t)bh*NS + kt0*32 + t] = 1.0f / s;
  }
}

// V (b,s,h,dk) -> Vf fragment-packed with inverse colsum folded in.
__global__ __launch_bounds__(256) void pack_v(const short* __restrict__ V,
                                              const float* __restrict__ invs,
                                              short* __restrict__ Vf){
  __shared__ short tile[64][66];
  const int sb = blockIdx.x * 64;
  const int bh = blockIdx.y;
  const int b = bh / NHD, h = bh % NHD;
  const int t = threadIdx.x;
  {
    int r = t >> 2, dkb = (t & 3) * 16;
    float iv = invs[(size_t)bh*NS + sb + r];
    const short* src = V + ((size_t)(b*NS + sb + r)*NHD + h)*NDK + dkb;
    short8 v0 = *(const short8*)src;
    short8 v1 = *(const short8*)(src + 8);
    #pragma unroll
    for (int j=0;j<8;++j) tile[r][dkb+j]   = f2b(b2f(v0[j]) * iv);
    #pragma unroll
    for (int j=0;j<8;++j) tile[r][dkb+8+j] = f2b(b2f(v1[j]) * iv);
  }
  __syncthreads();
  {
    const int c = t >> 6, l = t & 63;
    const int lq = l & 31, hf = l >> 5;
    const int dk = (c>>1)*32 + lq;
    #pragma unroll
    for (int kt_l = 0; kt_l < 2; ++kt_l){
      int kv0 = kt_l*32 + (c&1)*16 + hf*8;
      short8 o;
      #pragma unroll
      for (int j=0;j<8;++j) o[j] = tile[kv0+j][dk];
      *(short8*)(Vf + (((size_t)bh*64 + (sb>>5) + kt_l)*256 + c*64 + l)*8) = o;
    }
  }
}

// Pass C: grid (64,48): block = one 32-q tile; wave w covers kv-tiles
// [w*16, w*16+16); partial O combined via 16KB LDS tree. XCD-swizzled.
// min-waves=4: see pass_a note (8 forced a spill in round 4).
__global__ __launch_bounds__(256, 4) void pass_c(const short* __restrict__ Qf,
                                                 const short* __restrict__ Kf,
                                                 const short* __restrict__ Vf,
                                                 short* __restrict__ Hd){
  __shared__ float red[2][32][64];   // 16 KB
  const int t = threadIdx.x, w = t >> 6, l = t & 63;
  const int lq = l & 31, hf = l >> 5;
  const int linear = blockIdx.y * 64 + blockIdx.x;   // 3072 blocks
  const int c8 = linear & 7, j = linear >> 3;
  const int bh = c8 * 6 + (j >> 6);
  const int qt = j & 63;

  const short8* Qg = (const short8*)(Qf + ((size_t)bh*64 + qt)*2048);
  short8 qf4[4];
  #pragma unroll
  for (int c=0; c<4; ++c) qf4[c] = Qg[c*64 + l];

  const short8* Kb = (const short8*)(Kf + (size_t)bh*131072);
  const short8* Vb = (const short8*)(Vf + (size_t)bh*131072);

  f32x16 acc0 = {}, acc1 = {};   // heads[q][dk] halves

  for (int kt = w*16; kt < w*16 + 16; ++kt){
    const short8* Kg = Kb + kt*256;
    const short8* Vg = Vb + kt*256;
    short8 k0 = Kg[l], k1 = Kg[64+l], k2 = Kg[128+l], k3 = Kg[192+l];
    short8 v0 = Vg[l], v1 = Vg[64+l], v2 = Vg[128+l], v3 = Vg[192+l];

    f32x16 c = {};
    c = MFMA32(k0, qf4[0], c);
    c = MFMA32(k1, qf4[1], c);
    c = MFMA32(k2, qf4[2], c);
    c = MFMA32(k3, qf4[3], c);

    float p[16];
    #pragma unroll
    for (int r=0; r<16; ++r) p[r] = exp2f(c[r]);

    short8 pa[2];
    #pragma unroll
    for (int b2=0; b2<2; ++b2){
      uint32_t x0 = cvtpk(p[8*b2+0], p[8*b2+1]);
      uint32_t x1 = cvtpk(p[8*b2+2], p[8*b2+3]);
      uint32_t y0 = cvtpk(p[8*b2+4], p[8*b2+5]);
      uint32_t y1 = cvtpk(p[8*b2+6], p[8*b2+7]);
      uint2v r02 = __builtin_amdgcn_permlane32_swap(x0, y0, false, false);
      uint2v r13 = __builtin_amdgcn_permlane32_swap(x1, y1, false, false);
      pa[b2] = mk8(r02.x, r13.x, r02.y, r13.y);
    }
    acc0 = MFMA32(pa[0], v0, acc0);
    acc0 = MFMA32(pa[1], v1, acc0);
    acc1 = MFMA32(pa[0], v2, acc1);
    acc1 = MFMA32(pa[1], v3, acc1);
  }

  // cross-wave reduction: waves 2,3 -> LDS; waves 0,1 add; wave 1 -> LDS;
  // wave 0 adds and stores.
  if (w >= 2){
    #pragma unroll
    for (int r=0; r<16; ++r){
      red[w-2][r][l]    = acc0[r];
      red[w-2][16+r][l] = acc1[r];
    }
  }
  __syncthreads();
  if (w < 2){
    #pragma unroll
    for (int r=0; r<16; ++r){
      acc0[r] += red[w][r][l];
      acc1[r] += red[w][16+r][l];
    }
  }
  __syncthreads();
  if (w == 1){
    #pragma unroll
    for (int r=0; r<16; ++r){
      red[0][r][l]    = acc0[r];
      red[0][16+r][l] = acc1[r];
    }
  }
  __syncthreads();
  if (w == 0){
    #pragma unroll
    for (int r=0; r<16; ++r){
      acc0[r] += red[0][r][l];
      acc1[r] += red[0][16+r][l];
      int q = qt*32 + (r&3) + 8*(r>>2) + 4*hf;
      short* dst = Hd + ((size_t)bh*NS + q)*NDK;
      dst[lq]      = f2b(acc0[r]);
      dst[32 + lq] = f2b(acc1[r]);
    }
  }
}

extern "C" void kernel_launch(void* const* d_in, const int* in_sizes, int n_in,
                              void* d_out, int out_size, void* d_ws, size_t ws_size,
                              hipStream_t stream){
  (void)in_sizes; (void)n_in; (void)out_size; (void)ws_size;
  const float* x  = (const float*)d_in[0];
  const float* Wq = (const float*)d_in[1];
  const float* Wk = (const float*)d_in[2];
  const float* Wv = (const float*)d_in[3];
  const float* W0 = (const float*)d_in[4];

  char* ws = (char*)d_ws;
  const size_t SZ_X = (size_t)NB*NS*ND*2;   // 12,582,912 B
  const size_t SZ_W = (size_t)ND*ND*2;      //  1,179,648 B
  short* Xb   = (short*)(ws);               // reused as Hd after QKV GEMM
  short* Wqb  = (short*)(ws + SZ_X);
  short* Wkb  = (short*)(ws + SZ_X + 1*SZ_W);
  short* Wvb  = (short*)(ws + SZ_X + 2*SZ_W);
  short* W0b  = (short*)(ws + SZ_X + 3*SZ_W);
  short* Qf   = (short*)(ws + 1*SZ_X + 4*SZ_W);
  short* Kf   = (short*)(ws + 2*SZ_X + 4*SZ_W);
  short* V    = (short*)(ws + 3*SZ_X + 4*SZ_W);
  short* Vf   = (short*)(ws + 4*SZ_X + 4*SZ_W);
  float* invs = (float*)(ws + 5*SZ_X + 4*SZ_W);
  short* Hd   = Xb;
  float* out  = (float*)d_out;

  cast_f2bf<<<dim3(3072), dim3(256), 0, stream>>>(x,  Xb,  NB*NS*ND/8);
  cast_f2bf<<<dim3(288),  dim3(256), 0, stream>>>(Wq, Wqb, ND*ND/8);
  cast_f2bf<<<dim3(288),  dim3(256), 0, stream>>>(Wk, Wkb, ND*ND/8);
  cast_f2bf<<<dim3(288),  dim3(256), 0, stream>>>(Wv, Wvb, ND*ND/8);
  cast_f2bf<<<dim3(288),  dim3(256), 0, stream>>>(W0, W0b, ND*ND/8);

  gemm_qkv<<<dim3(64,18), dim3(256), 0, stream>>>(Xb, Wqb, Wkb, Wvb, Qf, Kf, V);
  pass_a<<<dim3(64,48), dim3(256), 0, stream>>>(Qf, Kf, invs);
  pack_v<<<dim3(32,48), dim3(256), 0, stream>>>(V, invs, Vf);
  pass_c<<<dim3(64,48), dim3(256), 0, stream>>>(Qf, Kf, Vf, Hd);
  gemm_out<<<dim3(64,6), dim3(256), 0, stream>>>(Hd, W0b, out);
}

// Round 7
// 224.837 us; speedup vs baseline: 1.3327x; 1.0302x over previous
//
#include <hip/hip_runtime.h>
#include <hip/hip_bf16.h>
#include <stdint.h>
#include <math.h>

// Problem dims (fixed)
#define NB  4
#define NS  2048
#define ND  768
#define NHD 12
#define NDK 64
#define NBH (NB*NHD)   // 48

// Q pre-scale: 1/sqrt(DK) * log2(e) so passes use raw exp2
#define QSCALE 0.180336879f

typedef short short8 __attribute__((ext_vector_type(8)));
typedef float f32x4  __attribute__((ext_vector_type(4)));
typedef float f32x16 __attribute__((ext_vector_type(16)));
typedef unsigned int uint2v __attribute__((ext_vector_type(2)));

#define MFMA16(a,b,c) __builtin_amdgcn_mfma_f32_16x16x32_bf16(a,b,c,0,0,0)
#define MFMA32(a,b,c) __builtin_amdgcn_mfma_f32_32x32x16_bf16(a,b,c,0,0,0)

__device__ __forceinline__ short f2b(float f){
  union { float f; uint32_t u; } v; v.f = f;
  uint32_t u = v.u + 0x7fffu + ((v.u >> 16) & 1u);  // RNE
  return (short)(u >> 16);
}
__device__ __forceinline__ float b2f(short s){
  union { float f; uint32_t u; } v; v.u = ((uint32_t)(unsigned short)s) << 16; return v.f;
}
__device__ __forceinline__ uint32_t cvtpk(float lo, float hi){
  uint32_t r;
  asm("v_cvt_pk_bf16_f32 %0, %1, %2" : "=v"(r) : "v"(lo), "v"(hi));
  return r;
}
__device__ __forceinline__ short8 mk8(uint32_t a, uint32_t b, uint32_t c, uint32_t d){
  union { uint32_t u[4]; short8 v; } x;
  x.u[0]=a; x.u[1]=b; x.u[2]=c; x.u[3]=d; return x.v;
}

__device__ __forceinline__ void gload16(const void* g, void* lds){
  __builtin_amdgcn_global_load_lds(
      (const __attribute__((address_space(1))) uint32_t*)g,
      (__attribute__((address_space(3))) uint32_t*)lds, 16, 0, 0);
}

// ---------------- fused fp32 -> bf16 cast of all 5 inputs ----------------
// (kept from round 6 — verified by per-thread index simulation; this is the
//  bisect candidate being tested in isolation this round)
__global__ __launch_bounds__(256) void cast_all(const float* __restrict__ x,
    const float* __restrict__ wq, const float* __restrict__ wk,
    const float* __restrict__ wv, const float* __restrict__ w0,
    short* __restrict__ xb, short* __restrict__ wqb, short* __restrict__ wkb,
    short* __restrict__ wvb, short* __restrict__ w0b){
  const int NX = NB*NS*ND/8;   // 786432 granules of 8
  const int NW = ND*ND/8;      // 73728
  int i = blockIdx.x*256 + threadIdx.x;
  const float* src; short* dst; int off;
  if (i < NX){ src = x; dst = xb; off = i; }
  else {
    int j = i - NX; int wsel = j / NW; off = j - wsel*NW;
    src = (wsel==0)?wq:((wsel==1)?wk:((wsel==2)?wv:w0));
    dst = (wsel==0)?wqb:((wsel==1)?wkb:((wsel==2)?wvb:w0b));
  }
  const f32x4* p = (const f32x4*)(src + (size_t)off*8);
  f32x4 v0 = p[0], v1 = p[1];
  short8 r;
  r[0]=f2b(v0[0]); r[1]=f2b(v0[1]); r[2]=f2b(v0[2]); r[3]=f2b(v0[3]);
  r[4]=f2b(v1[0]); r[5]=f2b(v1[1]); r[6]=f2b(v1[2]); r[7]=f2b(v1[3]);
  *(short8*)(dst + (size_t)off*8) = r;
}

// ---------------- 128x128x(K=768) bf16 GEMM core (m97 structure) ----------------
__device__ __forceinline__ void gemm128_core(const short* __restrict__ A,
                                             const short* __restrict__ Bw,
                                             int rowA0, int rowB0,
                                             short* As, short* Bs, f32x4 acc[4][4]){
  const int t = threadIdx.x;
  const int l  = t & 63;
  const int wm = ((t >> 7) & 1) * 64;
  const int wn = ((t >> 6) & 1) * 64;
  const int lr = l & 15, lg = l >> 4;
  #pragma unroll
  for (int mt=0; mt<4; ++mt)
    #pragma unroll
    for (int nt=0; nt<4; ++nt) acc[mt][nt] = (f32x4){0.f,0.f,0.f,0.f};

  for (int kt = 0; kt < 12; ++kt){
    #pragma unroll
    for (int c = 0; c < 4; ++c){
      int u  = c*256 + t;
      int m  = u >> 3;
      int kb = ((u & 7) << 4) ^ ((m & 7) << 4);   // inverse-swizzled source
      gload16((const char*)(A  + (size_t)(rowA0 + m)*768 + kt*64) + kb,
              (char*)As + ((c*256 + (t & 0xC0)) << 4));
      gload16((const char*)(Bw + (size_t)(rowB0 + m)*768 + kt*64) + kb,
              (char*)Bs + ((c*256 + (t & 0xC0)) << 4));
    }
    __syncthreads();
    short8 af[4][2], bf[4][2];
    #pragma unroll
    for (int mt=0; mt<4; ++mt)
      #pragma unroll
      for (int ks=0; ks<2; ++ks){
        int m  = wm + mt*16 + lr;
        int kb = (ks*32 + lg*8) * 2;
        af[mt][ks] = *(const short8*)((const char*)As + ((m*128 + kb) ^ ((m & 7) << 4)));
        int n  = wn + mt*16 + lr;
        bf[mt][ks] = *(const short8*)((const char*)Bs + ((n*128 + kb) ^ ((n & 7) << 4)));
      }
    #pragma unroll
    for (int mt=0; mt<4; ++mt)
      #pragma unroll
      for (int nt=0; nt<4; ++nt){
        acc[mt][nt] = MFMA16(af[mt][0], bf[nt][0], acc[mt][nt]);
        acc[mt][nt] = MFMA16(af[mt][1], bf[nt][1], acc[mt][nt]);
      }
    __syncthreads();
  }
}

// QKV fused: grid (64, 18). Q/K written in fragment-packed layout:
//   Xf[((bh*64 + (s>>5))*4 + (dk>>4))*512 + ((dk>>3)&1)*256 + (s&31)*8 + (dk&7)]
// Q pre-scaled by QSCALE. V written row-major (b,s,h,dk) for pack_v.
__global__ __launch_bounds__(256) void gemm_qkv(const short* __restrict__ Xb,
    const short* __restrict__ Wqb, const short* __restrict__ Wkb, const short* __restrict__ Wvb,
    short* __restrict__ Qf, short* __restrict__ Kf, short* __restrict__ V){
  __shared__ __align__(16) short As[128*64];
  __shared__ __align__(16) short Bs[128*64];
  const int wsel = blockIdx.y / 6;
  const int nb   = (blockIdx.y % 6) * 128;
  const short* W = (wsel==0) ? Wqb : ((wsel==1) ? Wkb : Wvb);
  f32x4 acc[4][4];
  gemm128_core(Xb, W, blockIdx.x*128, nb, As, Bs, acc);
  const int t = threadIdx.x, l = t & 63;
  const int wm = ((t>>7)&1)*64, wn = ((t>>6)&1)*64;
  const int lr = l & 15, lg = l >> 4;
  if (wsel == 2){
    #pragma unroll
    for (int mt=0; mt<4; ++mt)
      #pragma unroll
      for (int nt=0; nt<4; ++nt)
        #pragma unroll
        for (int r=0; r<4; ++r){
          int m = blockIdx.x*128 + wm + mt*16 + lg*4 + r;
          int n = nb + wn + nt*16 + lr;
          V[(size_t)m*768 + n] = f2b(acc[mt][nt][r]);
        }
  } else {
    short* O = (wsel==0) ? Qf : Kf;
    const float scl = (wsel==0) ? QSCALE : 1.0f;
    const int bh = (blockIdx.x >> 4)*NHD + ((nb + wn) >> 6);
    const int s0 = (blockIdx.x & 15)*128 + wm;
    short* Ob = O + (size_t)bh*131072;   // 64 kt * 2048
    #pragma unroll
    for (int mt=0; mt<4; ++mt)
      #pragma unroll
      for (int nt=0; nt<4; ++nt)
        #pragma unroll
        for (int r=0; r<4; ++r){
          int s  = s0 + mt*16 + lg*4 + r;
          int dk = nt*16 + lr;
          Ob[(size_t)((s>>5)*4 + (dk>>4))*512 + ((dk>>3)&1)*256 + (s&31)*8 + (dk&7)]
            = f2b(acc[mt][nt][r] * scl);
        }
  }
}

// Final projection: grid (64, 6). fp32 output.
__global__ __launch_bounds__(256) void gemm_out(const short* __restrict__ Hb,
    const short* __restrict__ W0b, float* __restrict__ out){
  __shared__ __align__(16) short As[128*64];
  __shared__ __align__(16) short Bs[128*64];
  const int nb = blockIdx.y * 128;
  f32x4 acc[4][4];
  gemm128_core(Hb, W0b, blockIdx.x*128, nb, As, Bs, acc);
  const int t = threadIdx.x, l = t & 63;
  const int wm = ((t>>7)&1)*64, wn = ((t>>6)&1)*64;
  const int lr = l & 15, lg = l >> 4;
  #pragma unroll
  for (int mt=0; mt<4; ++mt)
    #pragma unroll
    for (int nt=0; nt<4; ++nt)
      #pragma unroll
      for (int r=0; r<4; ++r){
        int m = blockIdx.x*128 + wm + mt*16 + lg*4 + r;
        int n = nb + wn + nt*16 + lr;
        out[(size_t)m*768 + n] = acc[mt][nt][r];
      }
}

// Pass A: colsum over the QUERY axis. grid (64,48): block = one 32-kv tile of
// one bh; wave w covers q-tiles [w*16, w*16+16). XCD-swizzled (bijective,
// 3072%8==0). ROUND-5-EXACT BODY (round-6 ping-pong prefetch restructure broke
// correctness — absmax 6.4e-2; reverted, do not reintroduce without disasm).
__global__ __launch_bounds__(256, 4) void pass_a(const short* __restrict__ Qf,
                                                 const short* __restrict__ Kf,
                                                 float* __restrict__ invs){
  __shared__ float redA[4][32];
  const int t = threadIdx.x, w = t >> 6, l = t & 63;
  const int lq = l & 31, hf = l >> 5;
  const int linear = blockIdx.y * 64 + blockIdx.x;   // 3072 blocks
  const int c8 = linear & 7, j = linear >> 3;
  const int bh = c8 * 6 + (j >> 6);
  const int kt0 = j & 63;

  const short8* Kg = (const short8*)(Kf + ((size_t)bh*64 + kt0)*2048);
  short8 kf4[4];
  #pragma unroll
  for (int c=0; c<4; ++c) kf4[c] = Kg[c*64 + l];

  float psum[16];
  #pragma unroll
  for (int r=0; r<16; ++r) psum[r] = 0.f;

  const short8* Qb = (const short8*)(Qf + (size_t)bh*131072);
  for (int qt = w*16; qt < w*16 + 16; ++qt){
    const short8* Qg = Qb + qt*256;
    short8 q0 = Qg[l], q1 = Qg[64+l], q2 = Qg[128+l], q3 = Qg[192+l];
    f32x16 c = {};
    c = MFMA32(kf4[0], q0, c);
    c = MFMA32(kf4[1], q1, c);
    c = MFMA32(kf4[2], q2, c);
    c = MFMA32(kf4[3], q3, c);
    #pragma unroll
    for (int r=0; r<16; ++r) psum[r] += exp2f(c[r]);
  }
  #pragma unroll
  for (int r=0; r<16; ++r){
    float v = psum[r];
    v += __shfl_xor(v, 1); v += __shfl_xor(v, 2);
    v += __shfl_xor(v, 4); v += __shfl_xor(v, 8); v += __shfl_xor(v, 16);
    if (lq == 0) redA[w][(r&3) + 8*(r>>2) + 4*hf] = v;
  }
  __syncthreads();
  if (t < 32){
    float s = redA[0][t] + redA[1][t] + redA[2][t] + redA[3][t];
    invs[(size_t)bh*NS + kt0*32 + t] = 1.0f / s;
  }
}

// V (b,s,h,dk) -> Vf fragment-packed with inverse colsum folded in.
__global__ __launch_bounds__(256) void pack_v(const short* __restrict__ V,
                                              const float* __restrict__ invs,
                                              short* __restrict__ Vf){
  __shared__ short tile[64][66];
  const int sb = blockIdx.x * 64;
  const int bh = blockIdx.y;
  const int b = bh / NHD, h = bh % NHD;
  const int t = threadIdx.x;
  {
    int r = t >> 2, dkb = (t & 3) * 16;
    float iv = invs[(size_t)bh*NS + sb + r];
    const short* src = V + ((size_t)(b*NS + sb + r)*NHD + h)*NDK + dkb;
    short8 v0 = *(const short8*)src;
    short8 v1 = *(const short8*)(src + 8);
    #pragma unroll
    for (int j=0;j<8;++j) tile[r][dkb+j]   = f2b(b2f(v0[j]) * iv);
    #pragma unroll
    for (int j=0;j<8;++j) tile[r][dkb+8+j] = f2b(b2f(v1[j]) * iv);
  }
  __syncthreads();
  {
    const int c = t >> 6, l = t & 63;
    const int lq = l & 31, hf = l >> 5;
    const int dk = (c>>1)*32 + lq;
    #pragma unroll
    for (int kt_l = 0; kt_l < 2; ++kt_l){
      int kv0 = kt_l*32 + (c&1)*16 + hf*8;
      short8 o;
      #pragma unroll
      for (int j=0;j<8;++j) o[j] = tile[kv0+j][dk];
      *(short8*)(Vf + (((size_t)bh*64 + (sb>>5) + kt_l)*256 + c*64 + l)*8) = o;
    }
  }
}

// Pass C: grid (64,48): block = one 32-q tile; wave w covers kv-tiles
// [w*16, w*16+16); partial O combined via 16KB LDS tree. XCD-swizzled.
// ROUND-5-EXACT BODY (see pass_a note on the round-6 revert).
__global__ __launch_bounds__(256, 4) void pass_c(const short* __restrict__ Qf,
                                                 const short* __restrict__ Kf,
                                                 const short* __restrict__ Vf,
                                                 short* __restrict__ Hd){
  __shared__ float red[2][32][64];   // 16 KB
  const int t = threadIdx.x, w = t >> 6, l = t & 63;
  const int lq = l & 31, hf = l >> 5;
  const int linear = blockIdx.y * 64 + blockIdx.x;   // 3072 blocks
  const int c8 = linear & 7, j = linear >> 3;
  const int bh = c8 * 6 + (j >> 6);
  const int qt = j & 63;

  const short8* Qg = (const short8*)(Qf + ((size_t)bh*64 + qt)*2048);
  short8 qf4[4];
  #pragma unroll
  for (int c=0; c<4; ++c) qf4[c] = Qg[c*64 + l];

  const short8* Kb = (const short8*)(Kf + (size_t)bh*131072);
  const short8* Vb = (const short8*)(Vf + (size_t)bh*131072);

  f32x16 acc0 = {}, acc1 = {};   // heads[q][dk] halves

  for (int kt = w*16; kt < w*16 + 16; ++kt){
    const short8* Kg = Kb + kt*256;
    const short8* Vg = Vb + kt*256;
    short8 k0 = Kg[l], k1 = Kg[64+l], k2 = Kg[128+l], k3 = Kg[192+l];
    short8 v0 = Vg[l], v1 = Vg[64+l], v2 = Vg[128+l], v3 = Vg[192+l];

    f32x16 c = {};
    c = MFMA32(k0, qf4[0], c);
    c = MFMA32(k1, qf4[1], c);
    c = MFMA32(k2, qf4[2], c);
    c = MFMA32(k3, qf4[3], c);

    float p[16];
    #pragma unroll
    for (int r=0; r<16; ++r) p[r] = exp2f(c[r]);

    short8 pa[2];
    #pragma unroll
    for (int b2=0; b2<2; ++b2){
      uint32_t x0 = cvtpk(p[8*b2+0], p[8*b2+1]);
      uint32_t x1 = cvtpk(p[8*b2+2], p[8*b2+3]);
      uint32_t y0 = cvtpk(p[8*b2+4], p[8*b2+5]);
      uint32_t y1 = cvtpk(p[8*b2+6], p[8*b2+7]);
      uint2v r02 = __builtin_amdgcn_permlane32_swap(x0, y0, false, false);
      uint2v r13 = __builtin_amdgcn_permlane32_swap(x1, y1, false, false);
      pa[b2] = mk8(r02.x, r13.x, r02.y, r13.y);
    }
    acc0 = MFMA32(pa[0], v0, acc0);
    acc0 = MFMA32(pa[1], v1, acc0);
    acc1 = MFMA32(pa[0], v2, acc1);
    acc1 = MFMA32(pa[1], v3, acc1);
  }

  // cross-wave reduction: waves 2,3 -> LDS; waves 0,1 add; wave 1 -> LDS;
  // wave 0 adds and stores.
  if (w >= 2){
    #pragma unroll
    for (int r=0; r<16; ++r){
      red[w-2][r][l]    = acc0[r];
      red[w-2][16+r][l] = acc1[r];
    }
  }
  __syncthreads();
  if (w < 2){
    #pragma unroll
    for (int r=0; r<16; ++r){
      acc0[r] += red[w][r][l];
      acc1[r] += red[w][16+r][l];
    }
  }
  __syncthreads();
  if (w == 1){
    #pragma unroll
    for (int r=0; r<16; ++r){
      red[0][r][l]    = acc0[r];
      red[0][16+r][l] = acc1[r];
    }
  }
  __syncthreads();
  if (w == 0){
    #pragma unroll
    for (int r=0; r<16; ++r){
      acc0[r] += red[0][r][l];
      acc1[r] += red[0][16+r][l];
      int q = qt*32 + (r&3) + 8*(r>>2) + 4*hf;
      short* dst = Hd + ((size_t)bh*NS + q)*NDK;
      dst[lq]      = f2b(acc0[r]);
      dst[32 + lq] = f2b(acc1[r]);
    }
  }
}

extern "C" void kernel_launch(void* const* d_in, const int* in_sizes, int n_in,
                              void* d_out, int out_size, void* d_ws, size_t ws_size,
                              hipStream_t stream){
  (void)in_sizes; (void)n_in; (void)out_size; (void)ws_size;
  const float* x  = (const float*)d_in[0];
  const float* Wq = (const float*)d_in[1];
  const float* Wk = (const float*)d_in[2];
  const float* Wv = (const float*)d_in[3];
  const float* W0 = (const float*)d_in[4];

  char* ws = (char*)d_ws;
  const size_t SZ_X = (size_t)NB*NS*ND*2;   // 12,582,912 B
  const size_t SZ_W = (size_t)ND*ND*2;      //  1,179,648 B
  short* Xb   = (short*)(ws);               // reused as Hd after QKV GEMM
  short* Wqb  = (short*)(ws + SZ_X);
  short* Wkb  = (short*)(ws + SZ_X + 1*SZ_W);
  short* Wvb  = (short*)(ws + SZ_X + 2*SZ_W);
  short* W0b  = (short*)(ws + SZ_X + 3*SZ_W);
  short* Qf   = (short*)(ws + 1*SZ_X + 4*SZ_W);
  short* Kf   = (short*)(ws + 2*SZ_X + 4*SZ_W);
  short* V    = (short*)(ws + 3*SZ_X + 4*SZ_W);
  short* Vf   = (short*)(ws + 4*SZ_X + 4*SZ_W);
  float* invs = (float*)(ws + 5*SZ_X + 4*SZ_W);
  short* Hd   = Xb;
  float* out  = (float*)d_out;

  // 786432 + 4*73728 = 1,081,344 granules / 256 = 4224 blocks (exact)
  cast_all<<<dim3(4224), dim3(256), 0, stream>>>(x, Wq, Wk, Wv, W0,
                                                 Xb, Wqb, Wkb, Wvb, W0b);

  gemm_qkv<<<dim3(64,18), dim3(256), 0, stream>>>(Xb, Wqb, Wkb, Wvb, Qf, Kf, V);
  pass_a<<<dim3(64,48), dim3(256), 0, stream>>>(Qf, Kf, invs);
  pack_v<<<dim3(32,48), dim3(256), 0, stream>>>(V, invs, Vf);
  pass_c<<<dim3(64,48), dim3(256), 0, stream>>>(Qf, Kf, Vf, Hd);
  gemm_out<<<dim3(64,6), dim3(256), 0, stream>>>(Hd, W0b, out);
}

// Round 9
// 204.777 us; speedup vs baseline: 1.4633x; 1.0980x over previous
//
#include <hip/hip_runtime.h>
#include <hip/hip_bf16.h>
#include <stdint.h>
#include <math.h>

// Problem dims (fixed)
#define NB  4
#define NS  2048
#define ND  768
#define NHD 12
#define NDK 64
#define NBH (NB*NHD)   // 48

// Q pre-scale: 1/sqrt(DK) * log2(e) so passes use raw exp2
#define QSCALE 0.180336879f

typedef short short8 __attribute__((ext_vector_type(8)));
typedef float f32x4  __attribute__((ext_vector_type(4)));
typedef float f32x16 __attribute__((ext_vector_type(16)));
typedef unsigned int uint2v __attribute__((ext_vector_type(2)));

#define MFMA16(a,b,c) __builtin_amdgcn_mfma_f32_16x16x32_bf16(a,b,c,0,0,0)
#define MFMA32(a,b,c) __builtin_amdgcn_mfma_f32_32x32x16_bf16(a,b,c,0,0,0)

// OCML native exp2: inlines to a single v_exp_f32 as a REAL VALU MachineInstr,
// so the compiler's MFMA->VALU hazard recognizer protects it.
// (Round-8 inline-asm v_exp_f32 was invisible to the hazard recognizer and
//  read MFMA results before retirement -> absmax 9.8e-2. BANNED.
//  Round-6 ping-pong prefetch also banned pending disasm.)
extern "C" __device__ float __ocml_native_exp2_f32(float);
__device__ __forceinline__ float nexp2(float x){ return __ocml_native_exp2_f32(x); }

__device__ __forceinline__ short f2b(float f){
  union { float f; uint32_t u; } v; v.f = f;
  uint32_t u = v.u + 0x7fffu + ((v.u >> 16) & 1u);  // RNE
  return (short)(u >> 16);
}
__device__ __forceinline__ float b2f(short s){
  union { float f; uint32_t u; } v; v.u = ((uint32_t)(unsigned short)s) << 16; return v.f;
}
__device__ __forceinline__ uint32_t cvtpk(float lo, float hi){
  uint32_t r;
  asm("v_cvt_pk_bf16_f32 %0, %1, %2" : "=v"(r) : "v"(lo), "v"(hi));
  return r;
}
__device__ __forceinline__ short8 mk8(uint32_t a, uint32_t b, uint32_t c, uint32_t d){
  union { uint32_t u[4]; short8 v; } x;
  x.u[0]=a; x.u[1]=b; x.u[2]=c; x.u[3]=d; return x.v;
}

__device__ __forceinline__ void gload16(const void* g, void* lds){
  __builtin_amdgcn_global_load_lds(
      (const __attribute__((address_space(1))) uint32_t*)g,
      (__attribute__((address_space(3))) uint32_t*)lds, 16, 0, 0);
}

// ---------------- fused fp32 -> bf16 cast of all 5 inputs ----------------
__global__ __launch_bounds__(256) void cast_all(const float* __restrict__ x,
    const float* __restrict__ wq, const float* __restrict__ wk,
    const float* __restrict__ wv, const float* __restrict__ w0,
    short* __restrict__ xb, short* __restrict__ wqb, short* __restrict__ wkb,
    short* __restrict__ wvb, short* __restrict__ w0b){
  const int NX = NB*NS*ND/8;   // 786432 granules of 8
  const int NW = ND*ND/8;      // 73728
  int i = blockIdx.x*256 + threadIdx.x;
  const float* src; short* dst; int off;
  if (i < NX){ src = x; dst = xb; off = i; }
  else {
    int j = i - NX; int wsel = j / NW; off = j - wsel*NW;
    src = (wsel==0)?wq:((wsel==1)?wk:((wsel==2)?wv:w0));
    dst = (wsel==0)?wqb:((wsel==1)?wkb:((wsel==2)?wvb:w0b));
  }
  const f32x4* p = (const f32x4*)(src + (size_t)off*8);
  f32x4 v0 = p[0], v1 = p[1];
  short8 r;
  r[0]=f2b(v0[0]); r[1]=f2b(v0[1]); r[2]=f2b(v0[2]); r[3]=f2b(v0[3]);
  r[4]=f2b(v1[0]); r[5]=f2b(v1[1]); r[6]=f2b(v1[2]); r[7]=f2b(v1[3]);
  *(short8*)(dst + (size_t)off*8) = r;
}

// ---------------- 128x128x(K=768) bf16 GEMM core (m97 structure) ----------------
__device__ __forceinline__ void gemm128_core(const short* __restrict__ A,
                                             const short* __restrict__ Bw,
                                             int rowA0, int rowB0,
                                             short* As, short* Bs, f32x4 acc[4][4]){
  const int t = threadIdx.x;
  const int l  = t & 63;
  const int wm = ((t >> 7) & 1) * 64;
  const int wn = ((t >> 6) & 1) * 64;
  const int lr = l & 15, lg = l >> 4;
  #pragma unroll
  for (int mt=0; mt<4; ++mt)
    #pragma unroll
    for (int nt=0; nt<4; ++nt) acc[mt][nt] = (f32x4){0.f,0.f,0.f,0.f};

  for (int kt = 0; kt < 12; ++kt){
    #pragma unroll
    for (int c = 0; c < 4; ++c){
      int u  = c*256 + t;
      int m  = u >> 3;
      int kb = ((u & 7) << 4) ^ ((m & 7) << 4);   // inverse-swizzled source
      gload16((const char*)(A  + (size_t)(rowA0 + m)*768 + kt*64) + kb,
              (char*)As + ((c*256 + (t & 0xC0)) << 4));
      gload16((const char*)(Bw + (size_t)(rowB0 + m)*768 + kt*64) + kb,
              (char*)Bs + ((c*256 + (t & 0xC0)) << 4));
    }
    __syncthreads();
    short8 af[4][2], bf[4][2];
    #pragma unroll
    for (int mt=0; mt<4; ++mt)
      #pragma unroll
      for (int ks=0; ks<2; ++ks){
        int m  = wm + mt*16 + lr;
        int kb = (ks*32 + lg*8) * 2;
        af[mt][ks] = *(const short8*)((const char*)As + ((m*128 + kb) ^ ((m & 7) << 4)));
        int n  = wn + mt*16 + lr;
        bf[mt][ks] = *(const short8*)((const char*)Bs + ((n*128 + kb) ^ ((n & 7) << 4)));
      }
    #pragma unroll
    for (int mt=0; mt<4; ++mt)
      #pragma unroll
      for (int nt=0; nt<4; ++nt){
        acc[mt][nt] = MFMA16(af[mt][0], bf[nt][0], acc[mt][nt]);
        acc[mt][nt] = MFMA16(af[mt][1], bf[nt][1], acc[mt][nt]);
      }
    __syncthreads();
  }
}

// QKV fused: grid (64, 18). Q/K written in fragment-packed layout:
//   Xf[((bh*64 + (s>>5))*4 + (dk>>4))*512 + ((dk>>3)&1)*256 + (s&31)*8 + (dk&7)]
// Q pre-scaled by QSCALE. V written row-major (b,s,h,dk) for pack_v.
__global__ __launch_bounds__(256) void gemm_qkv(const short* __restrict__ Xb,
    const short* __restrict__ Wqb, const short* __restrict__ Wkb, const short* __restrict__ Wvb,
    short* __restrict__ Qf, short* __restrict__ Kf, short* __restrict__ V){
  __shared__ __align__(16) short As[128*64];
  __shared__ __align__(16) short Bs[128*64];
  const int wsel = blockIdx.y / 6;
  const int nb   = (blockIdx.y % 6) * 128;
  const short* W = (wsel==0) ? Wqb : ((wsel==1) ? Wkb : Wvb);
  f32x4 acc[4][4];
  gemm128_core(Xb, W, blockIdx.x*128, nb, As, Bs, acc);
  const int t = threadIdx.x, l = t & 63;
  const int wm = ((t>>7)&1)*64, wn = ((t>>6)&1)*64;
  const int lr = l & 15, lg = l >> 4;
  if (wsel == 2){
    #pragma unroll
    for (int mt=0; mt<4; ++mt)
      #pragma unroll
      for (int nt=0; nt<4; ++nt)
        #pragma unroll
        for (int r=0; r<4; ++r){
          int m = blockIdx.x*128 + wm + mt*16 + lg*4 + r;
          int n = nb + wn + nt*16 + lr;
          V[(size_t)m*768 + n] = f2b(acc[mt][nt][r]);
        }
  } else {
    short* O = (wsel==0) ? Qf : Kf;
    const float scl = (wsel==0) ? QSCALE : 1.0f;
    const int bh = (blockIdx.x >> 4)*NHD + ((nb + wn) >> 6);
    const int s0 = (blockIdx.x & 15)*128 + wm;
    short* Ob = O + (size_t)bh*131072;   // 64 kt * 2048
    #pragma unroll
    for (int mt=0; mt<4; ++mt)
      #pragma unroll
      for (int nt=0; nt<4; ++nt)
        #pragma unroll
        for (int r=0; r<4; ++r){
          int s  = s0 + mt*16 + lg*4 + r;
          int dk = nt*16 + lr;
          Ob[(size_t)((s>>5)*4 + (dk>>4))*512 + ((dk>>3)&1)*256 + (s&31)*8 + (dk&7)]
            = f2b(acc[mt][nt][r] * scl);
        }
  }
}

// Final projection: grid (64, 6). fp32 output.
__global__ __launch_bounds__(256) void gemm_out(const short* __restrict__ Hb,
    const short* __restrict__ W0b, float* __restrict__ out){
  __shared__ __align__(16) short As[128*64];
  __shared__ __align__(16) short Bs[128*64];
  const int nb = blockIdx.y * 128;
  f32x4 acc[4][4];
  gemm128_core(Hb, W0b, blockIdx.x*128, nb, As, Bs, acc);
  const int t = threadIdx.x, l = t & 63;
  const int wm = ((t>>7)&1)*64, wn = ((t>>6)&1)*64;
  const int lr = l & 15, lg = l >> 4;
  #pragma unroll
  for (int mt=0; mt<4; ++mt)
    #pragma unroll
    for (int nt=0; nt<4; ++nt)
      #pragma unroll
      for (int r=0; r<4; ++r){
        int m = blockIdx.x*128 + wm + mt*16 + lg*4 + r;
        int n = nb + wn + nt*16 + lr;
        out[(size_t)m*768 + n] = acc[mt][nt][r];
      }
}

// Pass A: colsum over the QUERY axis. grid (64,48): block = one 32-kv tile of
// one bh; wave w covers q-tiles [w*16, w*16+16). XCD-swizzled (bijective,
// 3072%8==0). Round-7 structure; exp via __ocml_native_exp2_f32 (this round's
// single change).
__global__ __launch_bounds__(256, 4) void pass_a(const short* __restrict__ Qf,
                                                 const short* __restrict__ Kf,
                                                 float* __restrict__ invs){
  __shared__ float redA[4][32];
  const int t = threadIdx.x, w = t >> 6, l = t & 63;
  const int lq = l & 31, hf = l >> 5;
  const int linear = blockIdx.y * 64 + blockIdx.x;   // 3072 blocks
  const int c8 = linear & 7, j = linear >> 3;
  const int bh = c8 * 6 + (j >> 6);
  const int kt0 = j & 63;

  const short8* Kg = (const short8*)(Kf + ((size_t)bh*64 + kt0)*2048);
  short8 kf4[4];
  #pragma unroll
  for (int c=0; c<4; ++c) kf4[c] = Kg[c*64 + l];

  float psum[16];
  #pragma unroll
  for (int r=0; r<16; ++r) psum[r] = 0.f;

  const short8* Qb = (const short8*)(Qf + (size_t)bh*131072);
  for (int qt = w*16; qt < w*16 + 16; ++qt){
    const short8* Qg = Qb + qt*256;
    short8 q0 = Qg[l], q1 = Qg[64+l], q2 = Qg[128+l], q3 = Qg[192+l];
    f32x16 c = {};
    c = MFMA32(kf4[0], q0, c);
    c = MFMA32(kf4[1], q1, c);
    c = MFMA32(kf4[2], q2, c);
    c = MFMA32(kf4[3], q3, c);
    #pragma unroll
    for (int r=0; r<16; ++r) psum[r] += nexp2(c[r]);
  }
  #pragma unroll
  for (int r=0; r<16; ++r){
    float v = psum[r];
    v += __shfl_xor(v, 1); v += __shfl_xor(v, 2);
    v += __shfl_xor(v, 4); v += __shfl_xor(v, 8); v += __shfl_xor(v, 16);
    if (lq == 0) redA[w][(r&3) + 8*(r>>2) + 4*hf] = v;
  }
  __syncthreads();
  if (t < 32){
    float s = redA[0][t] + redA[1][t] + redA[2][t] + redA[3][t];
    invs[(size_t)bh*NS + kt0*32 + t] = 1.0f / s;
  }
}

// V (b,s,h,dk) -> Vf fragment-packed with inverse colsum folded in.
__global__ __launch_bounds__(256) void pack_v(const short* __restrict__ V,
                                              const float* __restrict__ invs,
                                              short* __restrict__ Vf){
  __shared__ short tile[64][66];
  const int sb = blockIdx.x * 64;
  const int bh = blockIdx.y;
  const int b = bh / NHD, h = bh % NHD;
  const int t = threadIdx.x;
  {
    int r = t >> 2, dkb = (t & 3) * 16;
    float iv = invs[(size_t)bh*NS + sb + r];
    const short* src = V + ((size_t)(b*NS + sb + r)*NHD + h)*NDK + dkb;
    short8 v0 = *(const short8*)src;
    short8 v1 = *(const short8*)(src + 8);
    #pragma unroll
    for (int j=0;j<8;++j) tile[r][dkb+j]   = f2b(b2f(v0[j]) * iv);
    #pragma unroll
    for (int j=0;j<8;++j) tile[r][dkb+8+j] = f2b(b2f(v1[j]) * iv);
  }
  __syncthreads();
  {
    const int c = t >> 6, l = t & 63;
    const int lq = l & 31, hf = l >> 5;
    const int dk = (c>>1)*32 + lq;
    #pragma unroll
    for (int kt_l = 0; kt_l < 2; ++kt_l){
      int kv0 = kt_l*32 + (c&1)*16 + hf*8;
      short8 o;
      #pragma unroll
      for (int j=0;j<8;++j) o[j] = tile[kv0+j][dk];
      *(short8*)(Vf + (((size_t)bh*64 + (sb>>5) + kt_l)*256 + c*64 + l)*8) = o;
    }
  }
}

// Pass C: grid (64,48): block = one 32-q tile; wave w covers kv-tiles
// [w*16, w*16+16); partial O combined via 16KB LDS tree. XCD-swizzled.
// Round-7 structure; exp via __ocml_native_exp2_f32 (this round's single change).
__global__ __launch_bounds__(256, 4) void pass_c(const short* __restrict__ Qf,
                                                 const short* __restrict__ Kf,
                                                 const short* __restrict__ Vf,
                                                 short* __restrict__ Hd){
  __shared__ float red[2][32][64];   // 16 KB
  const int t = threadIdx.x, w = t >> 6, l = t & 63;
  const int lq = l & 31, hf = l >> 5;
  const int linear = blockIdx.y * 64 + blockIdx.x;   // 3072 blocks
  const int c8 = linear & 7, j = linear >> 3;
  const int bh = c8 * 6 + (j >> 6);
  const int qt = j & 63;

  const short8* Qg = (const short8*)(Qf + ((size_t)bh*64 + qt)*2048);
  short8 qf4[4];
  #pragma unroll
  for (int c=0; c<4; ++c) qf4[c] = Qg[c*64 + l];

  const short8* Kb = (const short8*)(Kf + (size_t)bh*131072);
  const short8* Vb = (const short8*)(Vf + (size_t)bh*131072);

  f32x16 acc0 = {}, acc1 = {};   // heads[q][dk] halves

  for (int kt = w*16; kt < w*16 + 16; ++kt){
    const short8* Kg = Kb + kt*256;
    const short8* Vg = Vb + kt*256;
    short8 k0 = Kg[l], k1 = Kg[64+l], k2 = Kg[128+l], k3 = Kg[192+l];
    short8 v0 = Vg[l], v1 = Vg[64+l], v2 = Vg[128+l], v3 = Vg[192+l];

    f32x16 c = {};
    c = MFMA32(k0, qf4[0], c);
    c = MFMA32(k1, qf4[1], c);
    c = MFMA32(k2, qf4[2], c);
    c = MFMA32(k3, qf4[3], c);

    float p[16];
    #pragma unroll
    for (int r=0; r<16; ++r) p[r] = nexp2(c[r]);

    short8 pa[2];
    #pragma unroll
    for (int b2=0; b2<2; ++b2){
      uint32_t x0 = cvtpk(p[8*b2+0], p[8*b2+1]);
      uint32_t x1 = cvtpk(p[8*b2+2], p[8*b2+3]);
      uint32_t y0 = cvtpk(p[8*b2+4], p[8*b2+5]);
      uint32_t y1 = cvtpk(p[8*b2+6], p[8*b2+7]);
      uint2v r02 = __builtin_amdgcn_permlane32_swap(x0, y0, false, false);
      uint2v r13 = __builtin_amdgcn_permlane32_swap(x1, y1, false, false);
      pa[b2] = mk8(r02.x, r13.x, r02.y, r13.y);
    }
    acc0 = MFMA32(pa[0], v0, acc0);
    acc0 = MFMA32(pa[1], v1, acc0);
    acc1 = MFMA32(pa[0], v2, acc1);
    acc1 = MFMA32(pa[1], v3, acc1);
  }

  // cross-wave reduction: waves 2,3 -> LDS; waves 0,1 add; wave 1 -> LDS;
  // wave 0 adds and stores.
  if (w >= 2){
    #pragma unroll
    for (int r=0; r<16; ++r){
      red[w-2][r][l]    = acc0[r];
      red[w-2][16+r][l] = acc1[r];
    }
  }
  __syncthreads();
  if (w < 2){
    #pragma unroll
    for (int r=0; r<16; ++r){
      acc0[r] += red[w][r][l];
      acc1[r] += red[w][16+r][l];
    }
  }
  __syncthreads();
  if (w == 1){
    #pragma unroll
    for (int r=0; r<16; ++r){
      red[0][r][l]    = acc0[r];
      red[0][16+r][l] = acc1[r];
    }
  }
  __syncthreads();
  if (w == 0){
    #pragma unroll
    for (int r=0; r<16; ++r){
      acc0[r] += red[0][r][l];
      acc1[r] += red[0][16+r][l];
      int q = qt*32 + (r&3) + 8*(r>>2) + 4*hf;
      short* dst = Hd + ((size_t)bh*NS + q)*NDK;
      dst[lq]      = f2b(acc0[r]);
      dst[32 + lq] = f2b(acc1[r]);
    }
  }
}

extern "C" void kernel_launch(void* const* d_in, const int* in_sizes, int n_in,
                              void* d_out, int out_size, void* d_ws, size_t ws_size,
                              hipStream_t stream){
  (void)in_sizes; (void)n_in; (void)out_size; (void)ws_size;
  const float* x  = (const float*)d_in[0];
  const float* Wq = (const float*)d_in[1];
  const float* Wk = (const float*)d_in[2];
  const float* Wv = (const float*)d_in[3];
  const float* W0 = (const float*)d_in[4];

  char* ws = (char*)d_ws;
  const size_t SZ_X = (size_t)NB*NS*ND*2;   // 12,582,912 B
  const size_t SZ_W = (size_t)ND*ND*2;      //  1,179,648 B
  short* Xb   = (short*)(ws);               // reused as Hd after QKV GEMM
  short* Wqb  = (short*)(ws + SZ_X);
  short* Wkb  = (short*)(ws + SZ_X + 1*SZ_W);
  short* Wvb  = (short*)(ws + SZ_X + 2*SZ_W);
  short* W0b  = (short*)(ws + SZ_X + 3*SZ_W);
  short* Qf   = (short*)(ws + 1*SZ_X + 4*SZ_W);
  short* Kf   = (short*)(ws + 2*SZ_X + 4*SZ_W);
  short* V    = (short*)(ws + 3*SZ_X + 4*SZ_W);
  short* Vf   = (short*)(ws + 4*SZ_X + 4*SZ_W);
  float* invs = (float*)(ws + 5*SZ_X + 4*SZ_W);
  short* Hd   = Xb;
  float* out  = (float*)d_out;

  // 786432 + 4*73728 = 1,081,344 granules / 256 = 4224 blocks (exact)
  cast_all<<<dim3(4224), dim3(256), 0, stream>>>(x, Wq, Wk, Wv, W0,
                                                 Xb, Wqb, Wkb, Wvb, W0b);

  gemm_qkv<<<dim3(64,18), dim3(256), 0, stream>>>(Xb, Wqb, Wkb, Wvb, Qf, Kf, V);
  pass_a<<<dim3(64,48), dim3(256), 0, stream>>>(Qf, Kf, invs);
  pack_v<<<dim3(32,48), dim3(256), 0, stream>>>(V, invs, Vf);
  pass_c<<<dim3(64,48), dim3(256), 0, stream>>>(Qf, Kf, Vf, Hd);
  gemm_out<<<dim3(64,6), dim3(256), 0, stream>>>(Hd, W0b, out);
}

// Round 10
// 192.595 us; speedup vs baseline: 1.5558x; 1.0633x over previous
//
#include <hip/hip_runtime.h>
#include <hip/hip_bf16.h>
#include <stdint.h>
#include <math.h>

// Problem dims (fixed)
#define NB  4
#define NS  2048
#define ND  768
#define NHD 12
#define NDK 64
#define NBH (NB*NHD)   // 48

// Q pre-scale: 1/sqrt(DK) * log2(e) so passes use raw exp2
#define QSCALE 0.180336879f

typedef short short8 __attribute__((ext_vector_type(8)));
typedef float f32x4  __attribute__((ext_vector_type(4)));
typedef float f32x16 __attribute__((ext_vector_type(16)));
typedef unsigned int uint2v __attribute__((ext_vector_type(2)));

#define MFMA16(a,b,c) __builtin_amdgcn_mfma_f32_16x16x32_bf16(a,b,c,0,0,0)
#define MFMA32(a,b,c) __builtin_amdgcn_mfma_f32_32x32x16_bf16(a,b,c,0,0,0)

// OCML native exp2: inlines to a single v_exp_f32 as a REAL VALU MachineInstr,
// so the compiler's MFMA->VALU hazard recognizer protects it. (Round-8
// inline-asm v_exp_f32 bypassed the hazard recognizer -> absmax 9.8e-2. BANNED.
// Round-6 manual ping-pong prefetch also banned pending disasm.)
extern "C" __device__ float __ocml_native_exp2_f32(float);
__device__ __forceinline__ float nexp2(float x){ return __ocml_native_exp2_f32(x); }

__device__ __forceinline__ short f2b(float f){
  union { float f; uint32_t u; } v; v.f = f;
  uint32_t u = v.u + 0x7fffu + ((v.u >> 16) & 1u);  // RNE
  return (short)(u >> 16);
}
__device__ __forceinline__ float b2f(short s){
  union { float f; uint32_t u; } v; v.u = ((uint32_t)(unsigned short)s) << 16; return v.f;
}
__device__ __forceinline__ uint32_t cvtpk(float lo, float hi){
  uint32_t r;
  asm("v_cvt_pk_bf16_f32 %0, %1, %2" : "=v"(r) : "v"(lo), "v"(hi));
  return r;
}
__device__ __forceinline__ short8 mk8(uint32_t a, uint32_t b, uint32_t c, uint32_t d){
  union { uint32_t u[4]; short8 v; } x;
  x.u[0]=a; x.u[1]=b; x.u[2]=c; x.u[3]=d; return x.v;
}
// P[16 f32] -> two bf16x8 PV A-fragments (verified round-5 layout).
__device__ __forceinline__ void pack2(const float* p, short8& o0, short8& o1){
  uint32_t x0 = cvtpk(p[0], p[1]),  x1 = cvtpk(p[2], p[3]);
  uint32_t y0 = cvtpk(p[4], p[5]),  y1 = cvtpk(p[6], p[7]);
  uint2v r02 = __builtin_amdgcn_permlane32_swap(x0, y0, false, false);
  uint2v r13 = __builtin_amdgcn_permlane32_swap(x1, y1, false, false);
  o0 = mk8(r02.x, r13.x, r02.y, r13.y);
  uint32_t x2 = cvtpk(p[8],  p[9]),  x3 = cvtpk(p[10], p[11]);
  uint32_t y2 = cvtpk(p[12], p[13]), y3 = cvtpk(p[14], p[15]);
  uint2v r46 = __builtin_amdgcn_permlane32_swap(x2, y2, false, false);
  uint2v r57 = __builtin_amdgcn_permlane32_swap(x3, y3, false, false);
  o1 = mk8(r46.x, r57.x, r46.y, r57.y);
}

__device__ __forceinline__ void gload16(const void* g, void* lds){
  __builtin_amdgcn_global_load_lds(
      (const __attribute__((address_space(1))) uint32_t*)g,
      (__attribute__((address_space(3))) uint32_t*)lds, 16, 0, 0);
}

// ---------------- fused fp32 -> bf16 cast of all 5 inputs ----------------
__global__ __launch_bounds__(256) void cast_all(const float* __restrict__ x,
    const float* __restrict__ wq, const float* __restrict__ wk,
    const float* __restrict__ wv, const float* __restrict__ w0,
    short* __restrict__ xb, short* __restrict__ wqb, short* __restrict__ wkb,
    short* __restrict__ wvb, short* __restrict__ w0b){
  const int NX = NB*NS*ND/8;   // 786432 granules of 8
  const int NW = ND*ND/8;      // 73728
  int i = blockIdx.x*256 + threadIdx.x;
  const float* src; short* dst; int off;
  if (i < NX){ src = x; dst = xb; off = i; }
  else {
    int j = i - NX; int wsel = j / NW; off = j - wsel*NW;
    src = (wsel==0)?wq:((wsel==1)?wk:((wsel==2)?wv:w0));
    dst = (wsel==0)?wqb:((wsel==1)?wkb:((wsel==2)?wvb:w0b));
  }
  const f32x4* p = (const f32x4*)(src + (size_t)off*8);
  f32x4 v0 = p[0], v1 = p[1];
  short8 r;
  r[0]=f2b(v0[0]); r[1]=f2b(v0[1]); r[2]=f2b(v0[2]); r[3]=f2b(v0[3]);
  r[4]=f2b(v1[0]); r[5]=f2b(v1[1]); r[6]=f2b(v1[2]); r[7]=f2b(v1[3]);
  *(short8*)(dst + (size_t)off*8) = r;
}

// ---------------- 128x128x(K=768) bf16 GEMM core (m97 structure) ----------------
__device__ __forceinline__ void gemm128_core(const short* __restrict__ A,
                                             const short* __restrict__ Bw,
                                             int rowA0, int rowB0,
                                             short* As, short* Bs, f32x4 acc[4][4]){
  const int t = threadIdx.x;
  const int l  = t & 63;
  const int wm = ((t >> 7) & 1) * 64;
  const int wn = ((t >> 6) & 1) * 64;
  const int lr = l & 15, lg = l >> 4;
  #pragma unroll
  for (int mt=0; mt<4; ++mt)
    #pragma unroll
    for (int nt=0; nt<4; ++nt) acc[mt][nt] = (f32x4){0.f,0.f,0.f,0.f};

  for (int kt = 0; kt < 12; ++kt){
    #pragma unroll
    for (int c = 0; c < 4; ++c){
      int u  = c*256 + t;
      int m  = u >> 3;
      int kb = ((u & 7) << 4) ^ ((m & 7) << 4);   // inverse-swizzled source
      gload16((const char*)(A  + (size_t)(rowA0 + m)*768 + kt*64) + kb,
              (char*)As + ((c*256 + (t & 0xC0)) << 4));
      gload16((const char*)(Bw + (size_t)(rowB0 + m)*768 + kt*64) + kb,
              (char*)Bs + ((c*256 + (t & 0xC0)) << 4));
    }
    __syncthreads();
    short8 af[4][2], bf[4][2];
    #pragma unroll
    for (int mt=0; mt<4; ++mt)
      #pragma unroll
      for (int ks=0; ks<2; ++ks){
        int m  = wm + mt*16 + lr;
        int kb = (ks*32 + lg*8) * 2;
        af[mt][ks] = *(const short8*)((const char*)As + ((m*128 + kb) ^ ((m & 7) << 4)));
        int n  = wn + mt*16 + lr;
        bf[mt][ks] = *(const short8*)((const char*)Bs + ((n*128 + kb) ^ ((n & 7) << 4)));
      }
    #pragma unroll
    for (int mt=0; mt<4; ++mt)
      #pragma unroll
      for (int nt=0; nt<4; ++nt){
        acc[mt][nt] = MFMA16(af[mt][0], bf[nt][0], acc[mt][nt]);
        acc[mt][nt] = MFMA16(af[mt][1], bf[nt][1], acc[mt][nt]);
      }
    __syncthreads();
  }
}

// QKV fused: grid (64, 18). Q/K written in fragment-packed layout:
//   Xf[((bh*64 + (s>>5))*4 + (dk>>4))*512 + ((dk>>3)&1)*256 + (s&31)*8 + (dk&7)]
// Q pre-scaled by QSCALE. V written row-major (b,s,h,dk) for pack_v.
__global__ __launch_bounds__(256) void gemm_qkv(const short* __restrict__ Xb,
    const short* __restrict__ Wqb, const short* __restrict__ Wkb, const short* __restrict__ Wvb,
    short* __restrict__ Qf, short* __restrict__ Kf, short* __restrict__ V){
  __shared__ __align__(16) short As[128*64];
  __shared__ __align__(16) short Bs[128*64];
  const int wsel = blockIdx.y / 6;
  const int nb   = (blockIdx.y % 6) * 128;
  const short* W = (wsel==0) ? Wqb : ((wsel==1) ? Wkb : Wvb);
  f32x4 acc[4][4];
  gemm128_core(Xb, W, blockIdx.x*128, nb, As, Bs, acc);
  const int t = threadIdx.x, l = t & 63;
  const int wm = ((t>>7)&1)*64, wn = ((t>>6)&1)*64;
  const int lr = l & 15, lg = l >> 4;
  if (wsel == 2){
    #pragma unroll
    for (int mt=0; mt<4; ++mt)
      #pragma unroll
      for (int nt=0; nt<4; ++nt)
        #pragma unroll
        for (int r=0; r<4; ++r){
          int m = blockIdx.x*128 + wm + mt*16 + lg*4 + r;
          int n = nb + wn + nt*16 + lr;
          V[(size_t)m*768 + n] = f2b(acc[mt][nt][r]);
        }
  } else {
    short* O = (wsel==0) ? Qf : Kf;
    const float scl = (wsel==0) ? QSCALE : 1.0f;
    const int bh = (blockIdx.x >> 4)*NHD + ((nb + wn) >> 6);
    const int s0 = (blockIdx.x & 15)*128 + wm;
    short* Ob = O + (size_t)bh*131072;   // 64 kt * 2048
    #pragma unroll
    for (int mt=0; mt<4; ++mt)
      #pragma unroll
      for (int nt=0; nt<4; ++nt)
        #pragma unroll
        for (int r=0; r<4; ++r){
          int s  = s0 + mt*16 + lg*4 + r;
          int dk = nt*16 + lr;
          Ob[(size_t)((s>>5)*4 + (dk>>4))*512 + ((dk>>3)&1)*256 + (s&31)*8 + (dk&7)]
            = f2b(acc[mt][nt][r] * scl);
        }
  }
}

// Final projection: grid (64, 6). fp32 output.
__global__ __launch_bounds__(256) void gemm_out(const short* __restrict__ Hb,
    const short* __restrict__ W0b, float* __restrict__ out){
  __shared__ __align__(16) short As[128*64];
  __shared__ __align__(16) short Bs[128*64];
  const int nb = blockIdx.y * 128;
  f32x4 acc[4][4];
  gemm128_core(Hb, W0b, blockIdx.x*128, nb, As, Bs, acc);
  const int t = threadIdx.x, l = t & 63;
  const int wm = ((t>>7)&1)*64, wn = ((t>>6)&1)*64;
  const int lr = l & 15, lg = l >> 4;
  #pragma unroll
  for (int mt=0; mt<4; ++mt)
    #pragma unroll
    for (int nt=0; nt<4; ++nt)
      #pragma unroll
      for (int r=0; r<4; ++r){
        int m = blockIdx.x*128 + wm + mt*16 + lg*4 + r;
        int n = nb + wn + nt*16 + lr;
        out[(size_t)m*768 + n] = acc[mt][nt][r];
      }
}

// Pass A: colsum over the QUERY axis. grid (32,48): block = one PAIR of 32-kv
// tiles of one bh (shared Q granule stream serves both); wave w covers q-tiles
// [w*16, w*16+16). XCD-swizzled (bijective, 1536%8==0).
__global__ __launch_bounds__(256) void pass_a(const short* __restrict__ Qf,
                                              const short* __restrict__ Kf,
                                              float* __restrict__ invs){
  __shared__ float redA[2][4][32];
  const int t = threadIdx.x, w = t >> 6, l = t & 63;
  const int lq = l & 31, hf = l >> 5;
  const int linear = blockIdx.y * 32 + blockIdx.x;   // 1536 blocks
  const int c8 = linear & 7, j = linear >> 3;        // 192 per XCD group
  const int bh = c8 * 6 + (j >> 5);
  const int kp = j & 31;                              // kv-pair index

  const short8* KgA = (const short8*)(Kf + ((size_t)bh*64 + kp*2    )*2048);
  const short8* KgB = (const short8*)(Kf + ((size_t)bh*64 + kp*2 + 1)*2048);
  short8 kfA[4], kfB[4];
  #pragma unroll
  for (int c=0; c<4; ++c){ kfA[c] = KgA[c*64 + l]; kfB[c] = KgB[c*64 + l]; }

  float psA[16], psB[16];
  #pragma unroll
  for (int r=0; r<16; ++r){ psA[r] = 0.f; psB[r] = 0.f; }

  const short8* Qb = (const short8*)(Qf + (size_t)bh*131072);
  for (int qt = w*16; qt < w*16 + 16; ++qt){
    const short8* Qg = Qb + qt*256;
    short8 q0 = Qg[l], q1 = Qg[64+l], q2 = Qg[128+l], q3 = Qg[192+l];
    f32x16 cA = {}, cB = {};
    cA = MFMA32(kfA[0], q0, cA);  cB = MFMA32(kfB[0], q0, cB);
    cA = MFMA32(kfA[1], q1, cA);  cB = MFMA32(kfB[1], q1, cB);
    cA = MFMA32(kfA[2], q2, cA);  cB = MFMA32(kfB[2], q2, cB);
    cA = MFMA32(kfA[3], q3, cA);  cB = MFMA32(kfB[3], q3, cB);
    #pragma unroll
    for (int r=0; r<16; ++r){ psA[r] += nexp2(cA[r]); psB[r] += nexp2(cB[r]); }
  }
  #pragma unroll
  for (int r=0; r<16; ++r){
    float a = psA[r], b = psB[r];
    a += __shfl_xor(a, 1); a += __shfl_xor(a, 2);
    a += __shfl_xor(a, 4); a += __shfl_xor(a, 8); a += __shfl_xor(a, 16);
    b += __shfl_xor(b, 1); b += __shfl_xor(b, 2);
    b += __shfl_xor(b, 4); b += __shfl_xor(b, 8); b += __shfl_xor(b, 16);
    if (lq == 0){
      int kr = (r&3) + 8*(r>>2) + 4*hf;
      redA[0][w][kr] = a;
      redA[1][w][kr] = b;
    }
  }
  __syncthreads();
  if (t < 64){
    int kvt = t >> 5, kr = t & 31;
    float s = redA[kvt][0][kr] + redA[kvt][1][kr] + redA[kvt][2][kr] + redA[kvt][3][kr];
    invs[(size_t)bh*NS + (kp*2 + kvt)*32 + kr] = 1.0f / s;
  }
}

// V (b,s,h,dk) -> Vf fragment-packed with inverse colsum folded in.
__global__ __launch_bounds__(256) void pack_v(const short* __restrict__ V,
                                              const float* __restrict__ invs,
                                              short* __restrict__ Vf){
  __shared__ short tile[64][66];
  const int sb = blockIdx.x * 64;
  const int bh = blockIdx.y;
  const int b = bh / NHD, h = bh % NHD;
  const int t = threadIdx.x;
  {
    int r = t >> 2, dkb = (t & 3) * 16;
    float iv = invs[(size_t)bh*NS + sb + r];
    const short* src = V + ((size_t)(b*NS + sb + r)*NHD + h)*NDK + dkb;
    short8 v0 = *(const short8*)src;
    short8 v1 = *(const short8*)(src + 8);
    #pragma unroll
    for (int j=0;j<8;++j) tile[r][dkb+j]   = f2b(b2f(v0[j]) * iv);
    #pragma unroll
    for (int j=0;j<8;++j) tile[r][dkb+8+j] = f2b(b2f(v1[j]) * iv);
  }
  __syncthreads();
  {
    const int c = t >> 6, l = t & 63;
    const int lq = l & 31, hf = l >> 5;
    const int dk = (c>>1)*32 + lq;
    #pragma unroll
    for (int kt_l = 0; kt_l < 2; ++kt_l){
      int kv0 = kt_l*32 + (c&1)*16 + hf*8;
      short8 o;
      #pragma unroll
      for (int j=0;j<8;++j) o[j] = tile[kv0+j][dk];
      *(short8*)(Vf + (((size_t)bh*64 + (sb>>5) + kt_l)*256 + c*64 + l)*8) = o;
    }
  }
}

// pass_c cross-wave O-reduction + store for one q-tile (round-5-verified tail).
__device__ __forceinline__ void reduce_store(float (&red)[2][32][64],
                                             f32x16& a0, f32x16& a1,
                                             int w, int l, int lq, int hf,
                                             short* __restrict__ Hd,
                                             size_t bhNS, int qt){
  if (w >= 2){
    #pragma unroll
    for (int r=0; r<16; ++r){ red[w-2][r][l] = a0[r]; red[w-2][16+r][l] = a1[r]; }
  }
  __syncthreads();
  if (w < 2){
    #pragma unroll
    for (int r=0; r<16; ++r){ a0[r] += red[w][r][l]; a1[r] += red[w][16+r][l]; }
  }
  __syncthreads();
  if (w == 1){
    #pragma unroll
    for (int r=0; r<16; ++r){ red[0][r][l] = a0[r]; red[0][16+r][l] = a1[r]; }
  }
  __syncthreads();
  if (w == 0){
    #pragma unroll
    for (int r=0; r<16; ++r){
      a0[r] += red[0][r][l];
      a1[r] += red[0][16+r][l];
      int q = qt*32 + (r&3) + 8*(r>>2) + 4*hf;
      short* dst = Hd + (bhNS + q)*NDK;
      dst[lq]      = f2b(a0[r]);
      dst[32 + lq] = f2b(a1[r]);
    }
  }
}

// Pass C: grid (32,48): block = one PAIR of 32-q tiles of one bh; wave w covers
// kv-tiles [w*16, w*16+16) for BOTH q-tiles — K/V granules loaded once serve
// two independent QK/PV chains (halved load pressure, doubled ILP). Partial O
// combined via 16KB LDS tree, run twice (A then B). XCD-swizzled.
__global__ __launch_bounds__(256) void pass_c(const short* __restrict__ Qf,
                                              const short* __restrict__ Kf,
                                              const short* __restrict__ Vf,
                                              short* __restrict__ Hd){
  __shared__ float red[2][32][64];   // 16 KB, reused sequentially for A and B
  const int t = threadIdx.x, w = t >> 6, l = t & 63;
  const int lq = l & 31, hf = l >> 5;
  const int linear = blockIdx.y * 32 + blockIdx.x;   // 1536 blocks
  const int c8 = linear & 7, j = linear >> 3;
  const int bh = c8 * 6 + (j >> 5);
  const int qp = j & 31;                              // q-pair index

  const short8* QgA = (const short8*)(Qf + ((size_t)bh*64 + qp*2    )*2048);
  const short8* QgB = (const short8*)(Qf + ((size_t)bh*64 + qp*2 + 1)*2048);
  short8 qfA[4], qfB[4];
  #pragma unroll
  for (int c=0; c<4; ++c){ qfA[c] = QgA[c*64 + l]; qfB[c] = QgB[c*64 + l]; }

  const short8* Kb = (const short8*)(Kf + (size_t)bh*131072);
  const short8* Vb = (const short8*)(Vf + (size_t)bh*131072);

  f32x16 accA0 = {}, accA1 = {}, accB0 = {}, accB1 = {};

  for (int kt = w*16; kt < w*16 + 16; ++kt){
    const short8* Kg = Kb + kt*256;
    const short8* Vg = Vb + kt*256;
    short8 k0 = Kg[l], k1 = Kg[64+l], k2 = Kg[128+l], k3 = Kg[192+l];
    short8 v0 = Vg[l], v1 = Vg[64+l], v2 = Vg[128+l], v3 = Vg[192+l];

    f32x16 cA = {}, cB = {};
    cA = MFMA32(k0, qfA[0], cA);  cB = MFMA32(k0, qfB[0], cB);
    cA = MFMA32(k1, qfA[1], cA);  cB = MFMA32(k1, qfB[1], cB);
    cA = MFMA32(k2, qfA[2], cA);  cB = MFMA32(k2, qfB[2], cB);
    cA = MFMA32(k3, qfA[3], cA);  cB = MFMA32(k3, qfB[3], cB);

    float pA[16], pB[16];
    #pragma unroll
    for (int r=0; r<16; ++r){ pA[r] = nexp2(cA[r]); pB[r] = nexp2(cB[r]); }

    short8 paA0, paA1, paB0, paB1;
    pack2(pA, paA0, paA1);
    pack2(pB, paB0, paB1);

    accA0 = MFMA32(paA0, v0, accA0);
    accA0 = MFMA32(paA1, v1, accA0);
    accA1 = MFMA32(paA0, v2, accA1);
    accA1 = MFMA32(paA1, v3, accA1);
    accB0 = MFMA32(paB0, v0, accB0);
    accB0 = MFMA32(paB1, v1, accB0);
    accB1 = MFMA32(paB0, v2, accB1);
    accB1 = MFMA32(paB1, v3, accB1);
  }

  const size_t bhNS = (size_t)bh*NS;
  reduce_store(red, accA0, accA1, w, l, lq, hf, Hd, bhNS, qp*2);
  __syncthreads();
  reduce_store(red, accB0, accB1, w, l, lq, hf, Hd, bhNS, qp*2 + 1);
}

extern "C" void kernel_launch(void* const* d_in, const int* in_sizes, int n_in,
                              void* d_out, int out_size, void* d_ws, size_t ws_size,
                              hipStream_t stream){
  (void)in_sizes; (void)n_in; (void)out_size; (void)ws_size;
  const float* x  = (const float*)d_in[0];
  const float* Wq = (const float*)d_in[1];
  const float* Wk = (const float*)d_in[2];
  const float* Wv = (const float*)d_in[3];
  const float* W0 = (const float*)d_in[4];

  char* ws = (char*)d_ws;
  const size_t SZ_X = (size_t)NB*NS*ND*2;   // 12,582,912 B
  const size_t SZ_W = (size_t)ND*ND*2;      //  1,179,648 B
  short* Xb   = (short*)(ws);               // reused as Hd after QKV GEMM
  short* Wqb  = (short*)(ws + SZ_X);
  short* Wkb  = (short*)(ws + SZ_X + 1*SZ_W);
  short* Wvb  = (short*)(ws + SZ_X + 2*SZ_W);
  short* W0b  = (short*)(ws + SZ_X + 3*SZ_W);
  short* Qf   = (short*)(ws + 1*SZ_X + 4*SZ_W);
  short* Kf   = (short*)(ws + 2*SZ_X + 4*SZ_W);
  short* V    = (short*)(ws + 3*SZ_X + 4*SZ_W);
  short* Vf   = (short*)(ws + 4*SZ_X + 4*SZ_W);
  float* invs = (float*)(ws + 5*SZ_X + 4*SZ_W);
  short* Hd   = Xb;
  float* out  = (float*)d_out;

  // 786432 + 4*73728 = 1,081,344 granules / 256 = 4224 blocks (exact)
  cast_all<<<dim3(4224), dim3(256), 0, stream>>>(x, Wq, Wk, Wv, W0,
                                                 Xb, Wqb, Wkb, Wvb, W0b);

  gemm_qkv<<<dim3(64,18), dim3(256), 0, stream>>>(Xb, Wqb, Wkb, Wvb, Qf, Kf, V);
  pass_a<<<dim3(32,48), dim3(256), 0, stream>>>(Qf, Kf, invs);
  pack_v<<<dim3(32,48), dim3(256), 0, stream>>>(V, invs, Vf);
  pass_c<<<dim3(32,48), dim3(256), 0, stream>>>(Qf, Kf, Vf, Hd);
  gemm_out<<<dim3(64,6), dim3(256), 0, stream>>>(Hd, W0b, out);
}

// Round 11
// 180.435 us; speedup vs baseline: 1.6607x; 1.0674x over previous
//
#include <hip/hip_runtime.h>
#include <hip/hip_bf16.h>
#include <stdint.h>
#include <math.h>

// Problem dims (fixed)
#define NB  4
#define NS  2048
#define ND  768
#define NHD 12
#define NDK 64
#define NBH (NB*NHD)   // 48

// Q pre-scale: 1/sqrt(DK) * log2(e) so passes use raw exp2
#define QSCALE 0.180336879f

typedef short short8 __attribute__((ext_vector_type(8)));
typedef float f32x4  __attribute__((ext_vector_type(4)));
typedef float f32x16 __attribute__((ext_vector_type(16)));
typedef unsigned int uint2v __attribute__((ext_vector_type(2)));

#define MFMA16(a,b,c) __builtin_amdgcn_mfma_f32_16x16x32_bf16(a,b,c,0,0,0)
#define MFMA32(a,b,c) __builtin_amdgcn_mfma_f32_32x32x16_bf16(a,b,c,0,0,0)

// OCML native exp2: inlines to a single v_exp_f32 as a REAL VALU MachineInstr,
// so the compiler's MFMA->VALU hazard recognizer protects it. (Round-8
// inline-asm v_exp_f32 bypassed the hazard recognizer -> absmax 9.8e-2. BANNED.
// Round-6 manual ping-pong prefetch also banned pending disasm.)
extern "C" __device__ float __ocml_native_exp2_f32(float);
__device__ __forceinline__ float nexp2(float x){ return __ocml_native_exp2_f32(x); }

__device__ __forceinline__ short f2b(float f){
  union { float f; uint32_t u; } v; v.f = f;
  uint32_t u = v.u + 0x7fffu + ((v.u >> 16) & 1u);  // RNE
  return (short)(u >> 16);
}
__device__ __forceinline__ float b2f(short s){
  union { float f; uint32_t u; } v; v.u = ((uint32_t)(unsigned short)s) << 16; return v.f;
}
__device__ __forceinline__ uint32_t cvtpk(float lo, float hi){
  uint32_t r;
  asm("v_cvt_pk_bf16_f32 %0, %1, %2" : "=v"(r) : "v"(lo), "v"(hi));
  return r;
}
__device__ __forceinline__ short8 mk8(uint32_t a, uint32_t b, uint32_t c, uint32_t d){
  union { uint32_t u[4]; short8 v; } x;
  x.u[0]=a; x.u[1]=b; x.u[2]=c; x.u[3]=d; return x.v;
}
// P[16 f32] -> two bf16x8 PV A-fragments (verified round-5 layout).
__device__ __forceinline__ void pack2(const float* p, short8& o0, short8& o1){
  uint32_t x0 = cvtpk(p[0], p[1]),  x1 = cvtpk(p[2], p[3]);
  uint32_t y0 = cvtpk(p[4], p[5]),  y1 = cvtpk(p[6], p[7]);
  uint2v r02 = __builtin_amdgcn_permlane32_swap(x0, y0, false, false);
  uint2v r13 = __builtin_amdgcn_permlane32_swap(x1, y1, false, false);
  o0 = mk8(r02.x, r13.x, r02.y, r13.y);
  uint32_t x2 = cvtpk(p[8],  p[9]),  x3 = cvtpk(p[10], p[11]);
  uint32_t y2 = cvtpk(p[12], p[13]), y3 = cvtpk(p[14], p[15]);
  uint2v r46 = __builtin_amdgcn_permlane32_swap(x2, y2, false, false);
  uint2v r57 = __builtin_amdgcn_permlane32_swap(x3, y3, false, false);
  o1 = mk8(r46.x, r57.x, r46.y, r57.y);
}

__device__ __forceinline__ void gload16(const void* g, void* lds){
  __builtin_amdgcn_global_load_lds(
      (const __attribute__((address_space(1))) uint32_t*)g,
      (__attribute__((address_space(3))) uint32_t*)lds, 16, 0, 0);
}

// ---------------- fused fp32 -> bf16 cast of all 5 inputs ----------------
__global__ __launch_bounds__(256) void cast_all(const float* __restrict__ x,
    const float* __restrict__ wq, const float* __restrict__ wk,
    const float* __restrict__ wv, const float* __restrict__ w0,
    short* __restrict__ xb, short* __restrict__ wqb, short* __restrict__ wkb,
    short* __restrict__ wvb, short* __restrict__ w0b){
  const int NX = NB*NS*ND/8;   // 786432 granules of 8
  const int NW = ND*ND/8;      // 73728
  int i = blockIdx.x*256 + threadIdx.x;
  const float* src; short* dst; int off;
  if (i < NX){ src = x; dst = xb; off = i; }
  else {
    int j = i - NX; int wsel = j / NW; off = j - wsel*NW;
    src = (wsel==0)?wq:((wsel==1)?wk:((wsel==2)?wv:w0));
    dst = (wsel==0)?wqb:((wsel==1)?wkb:((wsel==2)?wvb:w0b));
  }
  const f32x4* p = (const f32x4*)(src + (size_t)off*8);
  f32x4 v0 = p[0], v1 = p[1];
  short8 r;
  r[0]=f2b(v0[0]); r[1]=f2b(v0[1]); r[2]=f2b(v0[2]); r[3]=f2b(v0[3]);
  r[4]=f2b(v1[0]); r[5]=f2b(v1[1]); r[6]=f2b(v1[2]); r[7]=f2b(v1[3]);
  *(short8*)(dst + (size_t)off*8) = r;
}

// ---------------- 128x128x(K=768) bf16 GEMM core (m97 structure) ----------------
__device__ __forceinline__ void gemm128_core(const short* __restrict__ A,
                                             const short* __restrict__ Bw,
                                             int rowA0, int rowB0,
                                             short* As, short* Bs, f32x4 acc[4][4]){
  const int t = threadIdx.x;
  const int l  = t & 63;
  const int wm = ((t >> 7) & 1) * 64;
  const int wn = ((t >> 6) & 1) * 64;
  const int lr = l & 15, lg = l >> 4;
  #pragma unroll
  for (int mt=0; mt<4; ++mt)
    #pragma unroll
    for (int nt=0; nt<4; ++nt) acc[mt][nt] = (f32x4){0.f,0.f,0.f,0.f};

  for (int kt = 0; kt < 12; ++kt){
    #pragma unroll
    for (int c = 0; c < 4; ++c){
      int u  = c*256 + t;
      int m  = u >> 3;
      int kb = ((u & 7) << 4) ^ ((m & 7) << 4);   // inverse-swizzled source
      gload16((const char*)(A  + (size_t)(rowA0 + m)*768 + kt*64) + kb,
              (char*)As + ((c*256 + (t & 0xC0)) << 4));
      gload16((const char*)(Bw + (size_t)(rowB0 + m)*768 + kt*64) + kb,
              (char*)Bs + ((c*256 + (t & 0xC0)) << 4));
    }
    __syncthreads();
    short8 af[4][2], bf[4][2];
    #pragma unroll
    for (int mt=0; mt<4; ++mt)
      #pragma unroll
      for (int ks=0; ks<2; ++ks){
        int m  = wm + mt*16 + lr;
        int kb = (ks*32 + lg*8) * 2;
        af[mt][ks] = *(const short8*)((const char*)As + ((m*128 + kb) ^ ((m & 7) << 4)));
        int n  = wn + mt*16 + lr;
        bf[mt][ks] = *(const short8*)((const char*)Bs + ((n*128 + kb) ^ ((n & 7) << 4)));
      }
    #pragma unroll
    for (int mt=0; mt<4; ++mt)
      #pragma unroll
      for (int nt=0; nt<4; ++nt){
        acc[mt][nt] = MFMA16(af[mt][0], bf[nt][0], acc[mt][nt]);
        acc[mt][nt] = MFMA16(af[mt][1], bf[nt][1], acc[mt][nt]);
      }
    __syncthreads();
  }
}

// QKV fused: grid (64, 18). Q/K written in fragment-packed layout:
//   Xf[((bh*64 + (s>>5))*4 + (dk>>4))*512 + ((dk>>3)&1)*256 + (s&31)*8 + (dk&7)]
// Q pre-scaled by QSCALE. V written row-major (b,s,h,dk) for pack_v.
__global__ __launch_bounds__(256) void gemm_qkv(const short* __restrict__ Xb,
    const short* __restrict__ Wqb, const short* __restrict__ Wkb, const short* __restrict__ Wvb,
    short* __restrict__ Qf, short* __restrict__ Kf, short* __restrict__ V){
  __shared__ __align__(16) short As[128*64];
  __shared__ __align__(16) short Bs[128*64];
  const int wsel = blockIdx.y / 6;
  const int nb   = (blockIdx.y % 6) * 128;
  const short* W = (wsel==0) ? Wqb : ((wsel==1) ? Wkb : Wvb);
  f32x4 acc[4][4];
  gemm128_core(Xb, W, blockIdx.x*128, nb, As, Bs, acc);
  const int t = threadIdx.x, l = t & 63;
  const int wm = ((t>>7)&1)*64, wn = ((t>>6)&1)*64;
  const int lr = l & 15, lg = l >> 4;
  if (wsel == 2){
    #pragma unroll
    for (int mt=0; mt<4; ++mt)
      #pragma unroll
      for (int nt=0; nt<4; ++nt)
        #pragma unroll
        for (int r=0; r<4; ++r){
          int m = blockIdx.x*128 + wm + mt*16 + lg*4 + r;
          int n = nb + wn + nt*16 + lr;
          V[(size_t)m*768 + n] = f2b(acc[mt][nt][r]);
        }
  } else {
    short* O = (wsel==0) ? Qf : Kf;
    const float scl = (wsel==0) ? QSCALE : 1.0f;
    const int bh = (blockIdx.x >> 4)*NHD + ((nb + wn) >> 6);
    const int s0 = (blockIdx.x & 15)*128 + wm;
    short* Ob = O + (size_t)bh*131072;   // 64 kt * 2048
    #pragma unroll
    for (int mt=0; mt<4; ++mt)
      #pragma unroll
      for (int nt=0; nt<4; ++nt)
        #pragma unroll
        for (int r=0; r<4; ++r){
          int s  = s0 + mt*16 + lg*4 + r;
          int dk = nt*16 + lr;
          Ob[(size_t)((s>>5)*4 + (dk>>4))*512 + ((dk>>3)&1)*256 + (s&31)*8 + (dk&7)]
            = f2b(acc[mt][nt][r] * scl);
        }
  }
}

// Final projection: grid (64, 6). fp32 output.
__global__ __launch_bounds__(256) void gemm_out(const short* __restrict__ Hb,
    const short* __restrict__ W0b, float* __restrict__ out){
  __shared__ __align__(16) short As[128*64];
  __shared__ __align__(16) short Bs[128*64];
  const int nb = blockIdx.y * 128;
  f32x4 acc[4][4];
  gemm128_core(Hb, W0b, blockIdx.x*128, nb, As, Bs, acc);
  const int t = threadIdx.x, l = t & 63;
  const int wm = ((t>>7)&1)*64, wn = ((t>>6)&1)*64;
  const int lr = l & 15, lg = l >> 4;
  #pragma unroll
  for (int mt=0; mt<4; ++mt)
    #pragma unroll
    for (int nt=0; nt<4; ++nt)
      #pragma unroll
      for (int r=0; r<4; ++r){
        int m = blockIdx.x*128 + wm + mt*16 + lg*4 + r;
        int n = nb + wn + nt*16 + lr;
        out[(size_t)m*768 + n] = acc[mt][nt][r];
      }
}

// Pass A: colsum over the QUERY axis. grid (32,48): block = one PAIR of 32-kv
// tiles of one bh (shared Q granule stream serves both); wave w covers q-tiles
// [w*16, w*16+16). XCD-swizzled (bijective, 1536%8==0).
// SEQUENTIAL A/B chains (round-10 interleave doubled live transients and
// dropped occupancy to ~2 waves/SIMD — neutral). min-waves=3 pins the budget.
__global__ __launch_bounds__(256, 3) void pass_a(const short* __restrict__ Qf,
                                                 const short* __restrict__ Kf,
                                                 float* __restrict__ invs){
  __shared__ float redA[2][4][32];
  const int t = threadIdx.x, w = t >> 6, l = t & 63;
  const int lq = l & 31, hf = l >> 5;
  const int linear = blockIdx.y * 32 + blockIdx.x;   // 1536 blocks
  const int c8 = linear & 7, j = linear >> 3;        // 192 per XCD group
  const int bh = c8 * 6 + (j >> 5);
  const int kp = j & 31;                              // kv-pair index

  const short8* KgA = (const short8*)(Kf + ((size_t)bh*64 + kp*2    )*2048);
  const short8* KgB = (const short8*)(Kf + ((size_t)bh*64 + kp*2 + 1)*2048);
  short8 kfA[4], kfB[4];
  #pragma unroll
  for (int c=0; c<4; ++c){ kfA[c] = KgA[c*64 + l]; kfB[c] = KgB[c*64 + l]; }

  float psA[16], psB[16];
  #pragma unroll
  for (int r=0; r<16; ++r){ psA[r] = 0.f; psB[r] = 0.f; }

  const short8* Qb = (const short8*)(Qf + (size_t)bh*131072);
  for (int qt = w*16; qt < w*16 + 16; ++qt){
    const short8* Qg = Qb + qt*256;
    short8 q0 = Qg[l], q1 = Qg[64+l], q2 = Qg[128+l], q3 = Qg[192+l];
    {
      f32x16 cA = {};
      cA = MFMA32(kfA[0], q0, cA);
      cA = MFMA32(kfA[1], q1, cA);
      cA = MFMA32(kfA[2], q2, cA);
      cA = MFMA32(kfA[3], q3, cA);
      #pragma unroll
      for (int r=0; r<16; ++r) psA[r] += nexp2(cA[r]);
    }
    {
      f32x16 cB = {};
      cB = MFMA32(kfB[0], q0, cB);
      cB = MFMA32(kfB[1], q1, cB);
      cB = MFMA32(kfB[2], q2, cB);
      cB = MFMA32(kfB[3], q3, cB);
      #pragma unroll
      for (int r=0; r<16; ++r) psB[r] += nexp2(cB[r]);
    }
  }
  #pragma unroll
  for (int r=0; r<16; ++r){
    float a = psA[r], b = psB[r];
    a += __shfl_xor(a, 1); a += __shfl_xor(a, 2);
    a += __shfl_xor(a, 4); a += __shfl_xor(a, 8); a += __shfl_xor(a, 16);
    b += __shfl_xor(b, 1); b += __shfl_xor(b, 2);
    b += __shfl_xor(b, 4); b += __shfl_xor(b, 8); b += __shfl_xor(b, 16);
    if (lq == 0){
      int kr = (r&3) + 8*(r>>2) + 4*hf;
      redA[0][w][kr] = a;
      redA[1][w][kr] = b;
    }
  }
  __syncthreads();
  if (t < 64){
    int kvt = t >> 5, kr = t & 31;
    float s = redA[kvt][0][kr] + redA[kvt][1][kr] + redA[kvt][2][kr] + redA[kvt][3][kr];
    invs[(size_t)bh*NS + (kp*2 + kvt)*32 + kr] = 1.0f / s;
  }
}

// V (b,s,h,dk) -> Vf fragment-packed with inverse colsum folded in.
__global__ __launch_bounds__(256) void pack_v(const short* __restrict__ V,
                                              const float* __restrict__ invs,
                                              short* __restrict__ Vf){
  __shared__ short tile[64][66];
  const int sb = blockIdx.x * 64;
  const int bh = blockIdx.y;
  const int b = bh / NHD, h = bh % NHD;
  const int t = threadIdx.x;
  {
    int r = t >> 2, dkb = (t & 3) * 16;
    float iv = invs[(size_t)bh*NS + sb + r];
    const short* src = V + ((size_t)(b*NS + sb + r)*NHD + h)*NDK + dkb;
    short8 v0 = *(const short8*)src;
    short8 v1 = *(const short8*)(src + 8);
    #pragma unroll
    for (int j=0;j<8;++j) tile[r][dkb+j]   = f2b(b2f(v0[j]) * iv);
    #pragma unroll
    for (int j=0;j<8;++j) tile[r][dkb+8+j] = f2b(b2f(v1[j]) * iv);
  }
  __syncthreads();
  {
    const int c = t >> 6, l = t & 63;
    const int lq = l & 31, hf = l >> 5;
    const int dk = (c>>1)*32 + lq;
    #pragma unroll
    for (int kt_l = 0; kt_l < 2; ++kt_l){
      int kv0 = kt_l*32 + (c&1)*16 + hf*8;
      short8 o;
      #pragma unroll
      for (int j=0;j<8;++j) o[j] = tile[kv0+j][dk];
      *(short8*)(Vf + (((size_t)bh*64 + (sb>>5) + kt_l)*256 + c*64 + l)*8) = o;
    }
  }
}

// pass_c cross-wave O-reduction + store for one q-tile (round-5-verified tail).
__device__ __forceinline__ void reduce_store(float (&red)[2][32][64],
                                             f32x16& a0, f32x16& a1,
                                             int w, int l, int lq, int hf,
                                             short* __restrict__ Hd,
                                             size_t bhNS, int qt){
  if (w >= 2){
    #pragma unroll
    for (int r=0; r<16; ++r){ red[w-2][r][l] = a0[r]; red[w-2][16+r][l] = a1[r]; }
  }
  __syncthreads();
  if (w < 2){
    #pragma unroll
    for (int r=0; r<16; ++r){ a0[r] += red[w][r][l]; a1[r] += red[w][16+r][l]; }
  }
  __syncthreads();
  if (w == 1){
    #pragma unroll
    for (int r=0; r<16; ++r){ red[0][r][l] = a0[r]; red[0][16+r][l] = a1[r]; }
  }
  __syncthreads();
  if (w == 0){
    #pragma unroll
    for (int r=0; r<16; ++r){
      a0[r] += red[0][r][l];
      a1[r] += red[0][16+r][l];
      int q = qt*32 + (r&3) + 8*(r>>2) + 4*hf;
      short* dst = Hd + (bhNS + q)*NDK;
      dst[lq]      = f2b(a0[r]);
      dst[32 + lq] = f2b(a1[r]);
    }
  }
}

// Pass C: grid (32,48): block = one PAIR of 32-q tiles of one bh; wave w covers
// kv-tiles [w*16, w*16+16) for BOTH q-tiles — K/V granules loaded once serve
// two QK/PV chains run SEQUENTIALLY (A fully, then B) so the c/p transient
// register set is reused between chains (round-10 interleave kept both live:
// ~2 waves/SIMD, neutral). min-waves=3 pins the unified budget (~170 cap,
// est. need ~144 — gentle; round-4's =8/64-cap spill tripwire: watch
// WRITE_SIZE). Partial O combined via 16KB LDS tree, run twice. XCD-swizzled.
__global__ __launch_bounds__(256, 3) void pass_c(const short* __restrict__ Qf,
                                                 const short* __restrict__ Kf,
                                                 const short* __restrict__ Vf,
                                                 short* __restrict__ Hd){
  __shared__ float red[2][32][64];   // 16 KB, reused sequentially for A and B
  const int t = threadIdx.x, w = t >> 6, l = t & 63;
  const int lq = l & 31, hf = l >> 5;
  const int linear = blockIdx.y * 32 + blockIdx.x;   // 1536 blocks
  const int c8 = linear & 7, j = linear >> 3;
  const int bh = c8 * 6 + (j >> 5);
  const int qp = j & 31;                              // q-pair index

  const short8* QgA = (const short8*)(Qf + ((size_t)bh*64 + qp*2    )*2048);
  const short8* QgB = (const short8*)(Qf + ((size_t)bh*64 + qp*2 + 1)*2048);
  short8 qfA[4], qfB[4];
  #pragma unroll
  for (int c=0; c<4; ++c){ qfA[c] = QgA[c*64 + l]; qfB[c] = QgB[c*64 + l]; }

  const short8* Kb = (const short8*)(Kf + (size_t)bh*131072);
  const short8* Vb = (const short8*)(Vf + (size_t)bh*131072);

  f32x16 accA0 = {}, accA1 = {}, accB0 = {}, accB1 = {};

  for (int kt = w*16; kt < w*16 + 16; ++kt){
    const short8* Kg = Kb + kt*256;
    const short8* Vg = Vb + kt*256;
    short8 k0 = Kg[l], k1 = Kg[64+l], k2 = Kg[128+l], k3 = Kg[192+l];
    short8 v0 = Vg[l], v1 = Vg[64+l], v2 = Vg[128+l], v3 = Vg[192+l];

    {  // chain A
      f32x16 cA = {};
      cA = MFMA32(k0, qfA[0], cA);
      cA = MFMA32(k1, qfA[1], cA);
      cA = MFMA32(k2, qfA[2], cA);
      cA = MFMA32(k3, qfA[3], cA);
      float pA[16];
      #pragma unroll
      for (int r=0; r<16; ++r) pA[r] = nexp2(cA[r]);
      short8 paA0, paA1;
      pack2(pA, paA0, paA1);
      accA0 = MFMA32(paA0, v0, accA0);
      accA0 = MFMA32(paA1, v1, accA0);
      accA1 = MFMA32(paA0, v2, accA1);
      accA1 = MFMA32(paA1, v3, accA1);
    }
    {  // chain B (reuses A's transient registers)
      f32x16 cB = {};
      cB = MFMA32(k0, qfB[0], cB);
      cB = MFMA32(k1, qfB[1], cB);
      cB = MFMA32(k2, qfB[2], cB);
      cB = MFMA32(k3, qfB[3], cB);
      float pB[16];
      #pragma unroll
      for (int r=0; r<16; ++r) pB[r] = nexp2(cB[r]);
      short8 paB0, paB1;
      pack2(pB, paB0, paB1);
      accB0 = MFMA32(paB0, v0, accB0);
      accB0 = MFMA32(paB1, v1, accB0);
      accB1 = MFMA32(paB0, v2, accB1);
      accB1 = MFMA32(paB1, v3, accB1);
    }
  }

  const size_t bhNS = (size_t)bh*NS;
  reduce_store(red, accA0, accA1, w, l, lq, hf, Hd, bhNS, qp*2);
  __syncthreads();
  reduce_store(red, accB0, accB1, w, l, lq, hf, Hd, bhNS, qp*2 + 1);
}

extern "C" void kernel_launch(void* const* d_in, const int* in_sizes, int n_in,
                              void* d_out, int out_size, void* d_ws, size_t ws_size,
                              hipStream_t stream){
  (void)in_sizes; (void)n_in; (void)out_size; (void)ws_size;
  const float* x  = (const float*)d_in[0];
  const float* Wq = (const float*)d_in[1];
  const float* Wk = (const float*)d_in[2];
  const float* Wv = (const float*)d_in[3];
  const float* W0 = (const float*)d_in[4];

  char* ws = (char*)d_ws;
  const size_t SZ_X = (size_t)NB*NS*ND*2;   // 12,582,912 B
  const size_t SZ_W = (size_t)ND*ND*2;      //  1,179,648 B
  short* Xb   = (short*)(ws);               // reused as Hd after QKV GEMM
  short* Wqb  = (short*)(ws + SZ_X);
  short* Wkb  = (short*)(ws + SZ_X + 1*SZ_W);
  short* Wvb  = (short*)(ws + SZ_X + 2*SZ_W);
  short* W0b  = (short*)(ws + SZ_X + 3*SZ_W);
  short* Qf   = (short*)(ws + 1*SZ_X + 4*SZ_W);
  short* Kf   = (short*)(ws + 2*SZ_X + 4*SZ_W);
  short* V    = (short*)(ws + 3*SZ_X + 4*SZ_W);
  short* Vf   = (short*)(ws + 4*SZ_X + 4*SZ_W);
  float* invs = (float*)(ws + 5*SZ_X + 4*SZ_W);
  short* Hd   = Xb;
  float* out  = (float*)d_out;

  // 786432 + 4*73728 = 1,081,344 granules / 256 = 4224 blocks (exact)
  cast_all<<<dim3(4224), dim3(256), 0, stream>>>(x, Wq, Wk, Wv, W0,
                                                 Xb, Wqb, Wkb, Wvb, W0b);

  gemm_qkv<<<dim3(64,18), dim3(256), 0, stream>>>(Xb, Wqb, Wkb, Wvb, Qf, Kf, V);
  pass_a<<<dim3(32,48), dim3(256), 0, stream>>>(Qf, Kf, invs);
  pack_v<<<dim3(32,48), dim3(256), 0, stream>>>(V, invs, Vf);
  pass_c<<<dim3(32,48), dim3(256), 0, stream>>>(Qf, Kf, Vf, Hd);
  gemm_out<<<dim3(64,6), dim3(256), 0, stream>>>(Hd, W0b, out);
}